// Round 9
// baseline (29176.288 us; speedup 1.0000x reference)
//
#include <hip/hip_runtime.h>
#include <hip/hip_bf16.h>
#include <hip/hip_fp16.h>

// CellTrack GNN, MI355X — R9: OUTPUT IS FP32.
// Root cause of R3-R8 plateau: absmax bit-identical (6.127930e-2) across six
// rounds with different numerics => error dominated by bytes never written.
// d_out is 500000 FP32 (2MB); writing packed bf16 left the 2nd MB at memset-0,
// absmax = max|bf16(ref)| over edges 250k..500k = constant 0.0612793 (just
// below stub's global 0.0644531; both exactly on the bf16 grid). The "(bf16)"
// in the test label is hard-coded text, not dtype evidence. R8's tight
// 256-edge on-device verification already proved the pipeline correct.
// R9: fp32 out; EB promoted bf16->fp16 (same bytes, 8x finer ULP);
// ws = X/XN/AGG fp32 + EB fp16 = 204.8MB (proven to fit in R4).

using bf16 = __hip_bfloat16;
using fp16 = __half;

#define NN 50000
#define EE 500000
#define EPSC 1e-8f

__device__ __forceinline__ float reluf(float v){ return v > 0.f ? v : 0.f; }

// ---------------------------------------------------------------------------
// LDS-tiled GEMM: C[ROWS][UDIM] = act(A[ROWS][kdim] @ W + b). A fp32 in LDS,
// row stride lda. W,b fp32 global, W row-major [kdim][UDIM]. 256 threads.
// Thread (ug=tid&15, eg=tid>>4) owns rows RPT*eg..+RPT-1, units ug*UPT..+UPT-1.
// ---------------------------------------------------------------------------
template<int ROWS, int UDIM, bool RELU, typename F>
__device__ __forceinline__ void tile_gemm(const float* sA, int lda, int kdim,
    float* sB, const float* __restrict__ W, const float* __restrict__ bias,
    int cnt, F emit)
{
  constexpr int UPT = UDIM / 16;
  constexpr int NF4 = UPT / 4;
  constexpr int RPT = ROWS / 16;
  constexpr int USH = (UDIM == 256) ? 8 : ((UDIM == 128) ? 7 : 6);
  const int tid = threadIdx.x;
  const int ug = tid & 15;
  const int eg = tid >> 4;
  float acc[RPT][UPT];
#pragma unroll
  for (int r = 0; r < RPT; ++r)
#pragma unroll
    for (int u = 0; u < UPT; ++u) acc[r][u] = 0.f;

  for (int k0 = 0; k0 < kdim; k0 += 16) {
    const int kt = (kdim - k0) < 16 ? (kdim - k0) : 16;
    __syncthreads();                      // sB reuse; orders prior sA writes
    for (int L = tid; L < kt * UDIM; L += 256) {
      const int kk = L >> USH;
      const int col = L & (UDIM - 1);
      sB[(kk << USH) + col] = W[(size_t)(k0 + kk) * UDIM + col];
    }
    __syncthreads();
    for (int kk = 0; kk < kt; ++kk) {
      float a[RPT];
#pragma unroll
      for (int r = 0; r < RPT; ++r)
        a[r] = sA[(RPT * eg + r) * lda + k0 + kk];
#pragma unroll
      for (int i = 0; i < NF4; ++i) {
        const float4 bv = *reinterpret_cast<const float4*>(&sB[(kk << USH) + ug * UPT + i * 4]);
#pragma unroll
        for (int r = 0; r < RPT; ++r) {
          acc[r][i*4+0] += a[r] * bv.x;
          acc[r][i*4+1] += a[r] * bv.y;
          acc[r][i*4+2] += a[r] * bv.z;
          acc[r][i*4+3] += a[r] * bv.w;
        }
      }
    }
  }
  __syncthreads();                        // all sA reads done before emit
#pragma unroll
  for (int r = 0; r < RPT; ++r) {
    const int e = RPT * eg + r;
    if (e < cnt) {
#pragma unroll
      for (int i = 0; i < NF4; ++i)
#pragma unroll
        for (int jj = 0; jj < 4; ++jj) {
          const int u = ug * UPT + i * 4 + jj;
          float v = acc[r][i * 4 + jj] + bias[u];
          if (RELU) v = reluf(v);
          emit(e, u, v);
        }
    }
  }
}

// ---------------------------------------------------------------------------
// K0: node encoder. 4 nodes/block (N = 4*12500). LDS ~21KB.
// ---------------------------------------------------------------------------
__global__ __launch_bounds__(256) void k_node_enc(
    const float* __restrict__ x1, const float* __restrict__ x2,
    const float* __restrict__ Wh1, const float* __restrict__ bh1,
    const float* __restrict__ Wh2, const float* __restrict__ bh2,
    const float* __restrict__ Wl1, const float* __restrict__ bl1,
    const float* __restrict__ Wl2, const float* __restrict__ bl2,
    float* __restrict__ X)
{
  __shared__ float sx1[4][13];
  __shared__ float sx2[4][128];
  __shared__ float sh1[4][257];
  __shared__ float sh2[4][257];
  const int tid = threadIdx.x;
  const int node0 = blockIdx.x * 4;

  if (tid < 52) {
    const int n = tid / 13, k = tid % 13;
    sx1[n][k] = x1[(node0 + n) * 13 + k];
  }
  for (int L = tid; L < 512; L += 256) {
    const int n = L >> 7, k = L & 127;
    sx2[n][k] = x2[(size_t)(node0 + n) * 128 + k];
  }
  __syncthreads();

  {
    const int u = tid;
    float a0 = 0.f, a1 = 0.f, a2 = 0.f, a3 = 0.f;
    for (int k = 0; k < 13; ++k) {
      const float w = Wh1[k * 256 + u];
      a0 += sx1[0][k] * w; a1 += sx1[1][k] * w;
      a2 += sx1[2][k] * w; a3 += sx1[3][k] * w;
    }
    const float b = bh1[u];
    sh1[0][u] = reluf(a0 + b); sh1[1][u] = reluf(a1 + b);
    sh1[2][u] = reluf(a2 + b); sh1[3][u] = reluf(a3 + b);

    float c0 = 0.f, c1 = 0.f, c2 = 0.f, c3 = 0.f;
    for (int k = 0; k < 128; ++k) {
      const float w = Wl1[k * 256 + u];
      c0 += sx2[0][k] * w; c1 += sx2[1][k] * w;
      c2 += sx2[2][k] * w; c3 += sx2[3][k] * w;
    }
    const float b2 = bl1[u];
    sh2[0][u] = reluf(c0 + b2); sh2[1][u] = reluf(c1 + b2);
    sh2[2][u] = reluf(c2 + b2); sh2[3][u] = reluf(c3 + b2);
  }
  __syncthreads();

  {
    const int c = tid & 127;
    const int half = tid >> 7;
    float a0 = 0.f, a1 = 0.f;
    if (c < 32) {
      for (int k = 0; k < 256; ++k) {
        const float w = Wh2[k * 32 + c];
        a0 += sh1[half][k] * w; a1 += sh1[half + 2][k] * w;
      }
      const float b = bh2[c];
      X[(size_t)(node0 + half) * 128 + c]     = a0 + b;
      X[(size_t)(node0 + half + 2) * 128 + c] = a1 + b;
    } else {
      const int cc = c - 32;
      for (int k = 0; k < 256; ++k) {
        const float w = Wl2[k * 96 + cc];
        a0 += sh2[half][k] * w; a1 += sh2[half + 2][k] * w;
      }
      const float b = bl2[cc];
      X[(size_t)(node0 + half) * 128 + c]     = a0 + b;
      X[(size_t)(node0 + half + 2) * 128 + c] = a1 + b;
    }
  }
}

// ---------------------------------------------------------------------------
// K2a: edge features (gathers + 2 cosine sims) + e-MLP (527->256->128) -> EB.
// 16 edges/block (E = 16*31250). sHid fp32 overlays sFeat post-barrier.
// LDS ~50.1KB.
// ---------------------------------------------------------------------------
__global__ __launch_bounds__(256) void k_edge_mlp(
    const float* __restrict__ x1, const float* __restrict__ x2,
    const int* __restrict__ ei, const float* __restrict__ X,
    const float* __restrict__ We1, const float* __restrict__ be1,
    const float* __restrict__ We2, const float* __restrict__ be2,
    fp16* __restrict__ EB)
{
  __shared__ float sFeat[16 * 527];
  __shared__ __align__(16) float sB[16 * 256];
  const int tid = threadIdx.x;
  const long e0 = (long)blockIdx.x * 16;
  const int n = tid >> 4;
  const int q = tid & 15;
  float* Arow = &sFeat[n * 527];

  {
    const int s = ei[e0 + n];
    const int t = ei[(long)EE + e0 + n];
    float ds = 0.f, ns = 0.f, nt = 0.f;
    for (int j = q; j < 141; j += 16) {
      const float a = (j < 13) ? x1[s * 13 + j] : x2[(size_t)s * 128 + (j - 13)];
      const float b = (j < 13) ? x1[t * 13 + j] : x2[(size_t)t * 128 + (j - 13)];
      ds += a * b; ns += a * a; nt += b * b;
      Arow[j] = fabsf(a - b);
    }
    ds += __shfl_xor(ds, 1); ds += __shfl_xor(ds, 2); ds += __shfl_xor(ds, 4); ds += __shfl_xor(ds, 8);
    ns += __shfl_xor(ns, 1); ns += __shfl_xor(ns, 2); ns += __shfl_xor(ns, 4); ns += __shfl_xor(ns, 8);
    nt += __shfl_xor(nt, 1); nt += __shfl_xor(nt, 2); nt += __shfl_xor(nt, 4); nt += __shfl_xor(nt, 8);
    if (q == 0)
      Arow[141] = ds / (fmaxf(sqrtf(ns), EPSC) * fmaxf(sqrtf(nt), EPSC));
    float ds2 = 0.f, ns2 = 0.f, nt2 = 0.f;
    for (int j = q; j < 128; j += 16) {
      const float a = X[(size_t)s * 128 + j];
      const float b = X[(size_t)t * 128 + j];
      ds2 += a * b; ns2 += a * a; nt2 += b * b;
      Arow[142 + j] = a; Arow[270 + j] = b; Arow[398 + j] = fabsf(a - b);
    }
    ds2 += __shfl_xor(ds2, 1); ds2 += __shfl_xor(ds2, 2); ds2 += __shfl_xor(ds2, 4); ds2 += __shfl_xor(ds2, 8);
    ns2 += __shfl_xor(ns2, 1); ns2 += __shfl_xor(ns2, 2); ns2 += __shfl_xor(ns2, 4); ns2 += __shfl_xor(ns2, 8);
    nt2 += __shfl_xor(nt2, 1); nt2 += __shfl_xor(nt2, 2); nt2 += __shfl_xor(nt2, 4); nt2 += __shfl_xor(nt2, 8);
    if (q == 0)
      Arow[526] = ds2 / (fmaxf(sqrtf(ns2), EPSC) * fmaxf(sqrtf(nt2), EPSC));
  }

  float* sHid = sFeat;   // fp32 hidden overlays feature region (post-barrier)
  tile_gemm<16, 256, true>(sFeat, 527, 527, sB, We1, be1, 16,
      [&](int e, int u, float v) { sHid[e * 257 + u] = v; });
  tile_gemm<16, 128, false>(sHid, 257, 256, sB, We2, be2, 16,
      [&](int e, int u, float v) { EB[(size_t)(e0 + e) * 128 + u] = __float2half(v); });
}

// ---------------------------------------------------------------------------
// K2b: msg = relu([xs | e] @ Wmsg + b); atomic segment-sum into AGG[trg].
// 32 edges/block (E = 32*15625). LDS ~41.2KB.
// ---------------------------------------------------------------------------
__global__ __launch_bounds__(256) void k_msg(
    const int* __restrict__ ei, const float* __restrict__ X,
    const fp16* __restrict__ EB,
    const float* __restrict__ Wmsg, const float* __restrict__ bmsg,
    float* __restrict__ AGG)
{
  __shared__ float sA[32 * 257];
  __shared__ __align__(16) float sB[16 * 128];
  __shared__ int strg[32];
  const int tid = threadIdx.x;
  const long e0 = (long)blockIdx.x * 32;
  const int n = tid >> 3;
  const int q = tid & 7;

  {
    const int s = ei[e0 + n];
    if (q == 0) strg[n] = ei[(long)EE + e0 + n];
    for (int j = q; j < 128; j += 8) {
      sA[n * 257 + j]       = X[(size_t)s * 128 + j];
      sA[n * 257 + 128 + j] = __half2float(EB[(size_t)(e0 + n) * 128 + j]);
    }
  }

  tile_gemm<32, 128, true>(sA, 257, 256, sB, Wmsg, bmsg, 32,
      [&](int e, int u, float v) {
        atomicAdd(&AGG[(size_t)strg[e] * 128 + u], v);
      });
}

// ---------------------------------------------------------------------------
// K3: xn = relu([x | agg] @ Wnode + b). 32 nodes/block. LDS ~41.2KB.
// ---------------------------------------------------------------------------
__global__ __launch_bounds__(256) void k_node_update(
    const float* __restrict__ X, const float* __restrict__ AGG,
    const float* __restrict__ Wnode, const float* __restrict__ bnode,
    float* __restrict__ XN)
{
  __shared__ float sA[32 * 257];
  __shared__ __align__(16) float sB[16 * 128];
  const int tid = threadIdx.x;
  const int n0 = blockIdx.x * 32;
  const int remn = NN - n0;
  const int cnt = remn < 32 ? remn : 32;
  const int n = tid >> 3;
  const int q = tid & 7;

  if (n < cnt) {
    for (int j = q; j < 128; j += 8) {
      sA[n * 257 + j]       = X[(size_t)(n0 + n) * 128 + j];
      sA[n * 257 + 128 + j] = AGG[(size_t)(n0 + n) * 128 + j];
    }
  } else {
    for (int j = q; j < 256; j += 8) sA[n * 257 + j] = 0.f;
  }

  tile_gemm<32, 128, true>(sA, 257, 256, sB, Wnode, bnode, cnt,
      [&](int e, int u, float v) { XN[(size_t)(n0 + e) * 128 + u] = v; });
}

// ---------------------------------------------------------------------------
// K4: e_mp = MLP([xn_s|xn_t|e], 384->256->128); pred = MLP(e_mp, 128->64->1).
// 16 edges/block. sE fp32 overlays sF. OUT IS FP32. LDS ~61.6KB.
// ---------------------------------------------------------------------------
__global__ __launch_bounds__(256) void k_empl(
    const int* __restrict__ ei, const float* __restrict__ XN,
    const fp16* __restrict__ EB,
    const float* __restrict__ Wmp1, const float* __restrict__ bmp1,
    const float* __restrict__ Wmp2, const float* __restrict__ bmp2,
    const float* __restrict__ Wc1, const float* __restrict__ bc1,
    const float* __restrict__ Wc2, const float* __restrict__ bc2,
    float* __restrict__ out)
{
  __shared__ float sF[16 * 385];
  __shared__ float sH2[16 * 257];
  __shared__ float sHC[16 * 65];
  __shared__ __align__(16) float sB[16 * 256];
  const int tid = threadIdx.x;
  const long e0 = (long)blockIdx.x * 16;
  const int n = tid >> 4;
  const int q = tid & 15;

  {
    const int s = ei[e0 + n];
    const int t = ei[(long)EE + e0 + n];
    for (int j = q; j < 128; j += 16) {
      sF[n * 385 + j]       = XN[(size_t)s * 128 + j];
      sF[n * 385 + 128 + j] = XN[(size_t)t * 128 + j];
      sF[n * 385 + 256 + j] = __half2float(EB[(size_t)(e0 + n) * 128 + j]);
    }
  }

  tile_gemm<16, 256, true>(sF, 385, 384, sB, Wmp1, bmp1, 16,
      [&](int e, int u, float v) { sH2[e * 257 + u] = v; });
  float* sE = sF;        // fp32 e_mp overlays sF (post-barrier safe)
  tile_gemm<16, 128, false>(sH2, 257, 256, sB, Wmp2, bmp2, 16,
      [&](int e, int u, float v) { sE[e * 129 + u] = v; });
  tile_gemm<16, 64, true>(sE, 129, 128, sB, Wc1, bc1, 16,
      [&](int e, int u, float v) { sHC[e * 65 + u] = v; });
  __syncthreads();
  if (tid < 16) {
    float acc = bc2[0];
    for (int k = 0; k < 64; ++k) acc += sHC[tid * 65 + k] * Wc2[k];
    out[e0 + tid] = acc;                 // FP32 output
  }
}

// ---------------------------------------------------------------------------
extern "C" void kernel_launch(void* const* d_in, const int* in_sizes, int n_in,
                              void* d_out, int out_size, void* d_ws, size_t ws_size,
                              hipStream_t stream)
{
  const float* x1  = (const float*)d_in[0];
  const float* x2  = (const float*)d_in[1];
  const int*   ei  = (const int*)d_in[2];
  const float* Wh1 = (const float*)d_in[3],  *bh1 = (const float*)d_in[4];
  const float* Wh2 = (const float*)d_in[5],  *bh2 = (const float*)d_in[6];
  const float* Wl1 = (const float*)d_in[7],  *bl1 = (const float*)d_in[8];
  const float* Wl2 = (const float*)d_in[9],  *bl2 = (const float*)d_in[10];
  const float* We1 = (const float*)d_in[11], *be1 = (const float*)d_in[12];
  const float* We2 = (const float*)d_in[13], *be2 = (const float*)d_in[14];
  const float* Wmsg = (const float*)d_in[15], *bmsg = (const float*)d_in[16];
  const float* Wnode = (const float*)d_in[17], *bnode = (const float*)d_in[18];
  const float* Wmp1 = (const float*)d_in[19], *bmp1 = (const float*)d_in[20];
  const float* Wmp2 = (const float*)d_in[21], *bmp2 = (const float*)d_in[22];
  const float* Wc1 = (const float*)d_in[23], *bc1 = (const float*)d_in[24];
  const float* Wc2 = (const float*)d_in[25], *bc2 = (const float*)d_in[26];
  float* out = (float*)d_out;            // FP32 output buffer

  // ws: X fp32 | XN fp32 | AGG fp32 | EB fp16 = 204.8MB (proven to fit)
  float* X   = (float*)d_ws;
  float* XN  = X  + (size_t)NN * 128;
  float* AGG = XN + (size_t)NN * 128;
  fp16*  EB  = (fp16*)(AGG + (size_t)NN * 128);

  hipMemsetAsync(AGG, 0, (size_t)NN * 128 * sizeof(float), stream);
  k_node_enc<<<12500, 256, 0, stream>>>(x1, x2, Wh1, bh1, Wh2, bh2,
                                        Wl1, bl1, Wl2, bl2, X);
  k_edge_mlp<<<31250, 256, 0, stream>>>(x1, x2, ei, X, We1, be1, We2, be2, EB);
  k_msg<<<15625, 256, 0, stream>>>(ei, X, EB, Wmsg, bmsg, AGG);
  k_node_update<<<1563, 256, 0, stream>>>(X, AGG, Wnode, bnode, XN);
  k_empl<<<31250, 256, 0, stream>>>(ei, XN, EB, Wmp1, bmp1, Wmp2, bmp2,
                                    Wc1, bc1, Wc2, bc2, out);
}

// Round 10
// 15155.545 us; speedup vs baseline: 1.9251x; 1.9251x over previous
//
#include <hip/hip_runtime.h>
#include <hip/hip_bf16.h>
#include <hip/hip_fp16.h>

// CellTrack GNN, MI355X — R10: bank-conflict fix + k_empl occupancy.
// R9 PASSED (absmax 2.44e-4, 29.2ms). Counters: SQ_LDS_BANK_CONFLICT 2.6-3.5e9
// (8-way on sB reads: ug*16 stride -> banks {0-3,16-19}), k_empl VGPR=256 +
// 61.9KB LDS -> 12% occupancy, VALUBusy 6.7%. R10: (1) chunk-permuted sB so
// thread ug reads float4 at i*64+ug*4 (banks 4ug, 2-way = free); (2) k_empl
// LDS overlays (H2/e_mp/HC inside sF) -> 41.2KB + __launch_bounds__(256,3).
// ws: X fp32 | XN fp32 | AGG fp32 | EB fp16 = 204.8MB (proven).

using bf16 = __hip_bfloat16;
using fp16 = __half;

#define NN 50000
#define EE 500000
#define EPSC 1e-8f

__device__ __forceinline__ float reluf(float v){ return v > 0.f ? v : 0.f; }

// ---------------------------------------------------------------------------
// LDS-tiled GEMM: C[ROWS][UDIM] = act(A[ROWS][kdim] @ W + b). A fp32 in LDS,
// row stride lda. W,b fp32 global, W row-major [kdim][UDIM]. 256 threads.
// Thread (ug=tid&15, eg=tid>>4) owns rows RPT*eg..+RPT-1, units ug*UPT..+UPT-1.
// sB k-tile is CHUNK-PERMUTED: col -> pos so that thread ug's i-th float4
// lives at pos i*64 + ug*4 (banks 4ug%32: 2-way aliasing only, free per m136).
//   UDIM=256: pos = ((col>>2)&3)*64 + ((col>>4)&15)*4 + (col&3)
//   UDIM=128: pos = ((col>>2)&1)*64 + ((col>>3)&15)*4 + (col&3)
//   UDIM=64 : pos = col (identity; reads at ug*4 already conflict-free)
// ---------------------------------------------------------------------------
template<int ROWS, int UDIM, bool RELU, typename F>
__device__ __forceinline__ void tile_gemm(const float* sA, int lda, int kdim,
    float* sB, const float* __restrict__ W, const float* __restrict__ bias,
    int cnt, F emit)
{
  constexpr int UPT = UDIM / 16;
  constexpr int NF4 = UPT / 4;
  constexpr int RPT = ROWS / 16;
  constexpr int USH = (UDIM == 256) ? 8 : ((UDIM == 128) ? 7 : 6);
  const int tid = threadIdx.x;
  const int ug = tid & 15;
  const int eg = tid >> 4;
  float acc[RPT][UPT];
#pragma unroll
  for (int r = 0; r < RPT; ++r)
#pragma unroll
    for (int u = 0; u < UPT; ++u) acc[r][u] = 0.f;

  for (int k0 = 0; k0 < kdim; k0 += 16) {
    const int kt = (kdim - k0) < 16 ? (kdim - k0) : 16;
    __syncthreads();                      // sB reuse; orders prior sA writes
    for (int L = tid; L < kt * UDIM; L += 256) {
      const int kk = L >> USH;
      const int col = L & (UDIM - 1);
      int pos;
      if (UDIM == 256)      pos = ((col >> 2) & 3) * 64 + ((col >> 4) & 15) * 4 + (col & 3);
      else if (UDIM == 128) pos = ((col >> 2) & 1) * 64 + ((col >> 3) & 15) * 4 + (col & 3);
      else                  pos = col;
      sB[(kk << USH) + pos] = W[(size_t)(k0 + kk) * UDIM + col];
    }
    __syncthreads();
    for (int kk = 0; kk < kt; ++kk) {
      float a[RPT];
#pragma unroll
      for (int r = 0; r < RPT; ++r)
        a[r] = sA[(RPT * eg + r) * lda + k0 + kk];
#pragma unroll
      for (int i = 0; i < NF4; ++i) {
        const float4 bv = *reinterpret_cast<const float4*>(&sB[(kk << USH) + i * 64 + ug * 4]);
#pragma unroll
        for (int r = 0; r < RPT; ++r) {
          acc[r][i*4+0] += a[r] * bv.x;
          acc[r][i*4+1] += a[r] * bv.y;
          acc[r][i*4+2] += a[r] * bv.z;
          acc[r][i*4+3] += a[r] * bv.w;
        }
      }
    }
  }
  __syncthreads();                        // all sA reads done before emit
#pragma unroll
  for (int r = 0; r < RPT; ++r) {
    const int e = RPT * eg + r;
    if (e < cnt) {
#pragma unroll
      for (int i = 0; i < NF4; ++i)
#pragma unroll
        for (int jj = 0; jj < 4; ++jj) {
          const int u = ug * UPT + i * 4 + jj;
          float v = acc[r][i * 4 + jj] + bias[u];
          if (RELU) v = reluf(v);
          emit(e, u, v);
        }
    }
  }
}

// ---------------------------------------------------------------------------
// K0: node encoder. 4 nodes/block (N = 4*12500). LDS ~21KB.
// ---------------------------------------------------------------------------
__global__ __launch_bounds__(256) void k_node_enc(
    const float* __restrict__ x1, const float* __restrict__ x2,
    const float* __restrict__ Wh1, const float* __restrict__ bh1,
    const float* __restrict__ Wh2, const float* __restrict__ bh2,
    const float* __restrict__ Wl1, const float* __restrict__ bl1,
    const float* __restrict__ Wl2, const float* __restrict__ bl2,
    float* __restrict__ X)
{
  __shared__ float sx1[4][13];
  __shared__ float sx2[4][128];
  __shared__ float sh1[4][257];
  __shared__ float sh2[4][257];
  const int tid = threadIdx.x;
  const int node0 = blockIdx.x * 4;

  if (tid < 52) {
    const int n = tid / 13, k = tid % 13;
    sx1[n][k] = x1[(node0 + n) * 13 + k];
  }
  for (int L = tid; L < 512; L += 256) {
    const int n = L >> 7, k = L & 127;
    sx2[n][k] = x2[(size_t)(node0 + n) * 128 + k];
  }
  __syncthreads();

  {
    const int u = tid;
    float a0 = 0.f, a1 = 0.f, a2 = 0.f, a3 = 0.f;
    for (int k = 0; k < 13; ++k) {
      const float w = Wh1[k * 256 + u];
      a0 += sx1[0][k] * w; a1 += sx1[1][k] * w;
      a2 += sx1[2][k] * w; a3 += sx1[3][k] * w;
    }
    const float b = bh1[u];
    sh1[0][u] = reluf(a0 + b); sh1[1][u] = reluf(a1 + b);
    sh1[2][u] = reluf(a2 + b); sh1[3][u] = reluf(a3 + b);

    float c0 = 0.f, c1 = 0.f, c2 = 0.f, c3 = 0.f;
    for (int k = 0; k < 128; ++k) {
      const float w = Wl1[k * 256 + u];
      c0 += sx2[0][k] * w; c1 += sx2[1][k] * w;
      c2 += sx2[2][k] * w; c3 += sx2[3][k] * w;
    }
    const float b2 = bl1[u];
    sh2[0][u] = reluf(c0 + b2); sh2[1][u] = reluf(c1 + b2);
    sh2[2][u] = reluf(c2 + b2); sh2[3][u] = reluf(c3 + b2);
  }
  __syncthreads();

  {
    const int c = tid & 127;
    const int half = tid >> 7;
    float a0 = 0.f, a1 = 0.f;
    if (c < 32) {
      for (int k = 0; k < 256; ++k) {
        const float w = Wh2[k * 32 + c];
        a0 += sh1[half][k] * w; a1 += sh1[half + 2][k] * w;
      }
      const float b = bh2[c];
      X[(size_t)(node0 + half) * 128 + c]     = a0 + b;
      X[(size_t)(node0 + half + 2) * 128 + c] = a1 + b;
    } else {
      const int cc = c - 32;
      for (int k = 0; k < 256; ++k) {
        const float w = Wl2[k * 96 + cc];
        a0 += sh2[half][k] * w; a1 += sh2[half + 2][k] * w;
      }
      const float b = bl2[cc];
      X[(size_t)(node0 + half) * 128 + c]     = a0 + b;
      X[(size_t)(node0 + half + 2) * 128 + c] = a1 + b;
    }
  }
}

// ---------------------------------------------------------------------------
// K2a: edge features (gathers + 2 cosine sims) + e-MLP (527->256->128) -> EB.
// 16 edges/block (E = 16*31250). sHid fp32 overlays sFeat post-barrier.
// LDS ~50.1KB (3 blocks/CU).
// ---------------------------------------------------------------------------
__global__ __launch_bounds__(256, 3) void k_edge_mlp(
    const float* __restrict__ x1, const float* __restrict__ x2,
    const int* __restrict__ ei, const float* __restrict__ X,
    const float* __restrict__ We1, const float* __restrict__ be1,
    const float* __restrict__ We2, const float* __restrict__ be2,
    fp16* __restrict__ EB)
{
  __shared__ float sFeat[16 * 527];
  __shared__ __align__(16) float sB[16 * 256];
  const int tid = threadIdx.x;
  const long e0 = (long)blockIdx.x * 16;
  const int n = tid >> 4;
  const int q = tid & 15;
  float* Arow = &sFeat[n * 527];

  {
    const int s = ei[e0 + n];
    const int t = ei[(long)EE + e0 + n];
    float ds = 0.f, ns = 0.f, nt = 0.f;
    for (int j = q; j < 141; j += 16) {
      const float a = (j < 13) ? x1[s * 13 + j] : x2[(size_t)s * 128 + (j - 13)];
      const float b = (j < 13) ? x1[t * 13 + j] : x2[(size_t)t * 128 + (j - 13)];
      ds += a * b; ns += a * a; nt += b * b;
      Arow[j] = fabsf(a - b);
    }
    ds += __shfl_xor(ds, 1); ds += __shfl_xor(ds, 2); ds += __shfl_xor(ds, 4); ds += __shfl_xor(ds, 8);
    ns += __shfl_xor(ns, 1); ns += __shfl_xor(ns, 2); ns += __shfl_xor(ns, 4); ns += __shfl_xor(ns, 8);
    nt += __shfl_xor(nt, 1); nt += __shfl_xor(nt, 2); nt += __shfl_xor(nt, 4); nt += __shfl_xor(nt, 8);
    if (q == 0)
      Arow[141] = ds / (fmaxf(sqrtf(ns), EPSC) * fmaxf(sqrtf(nt), EPSC));
    float ds2 = 0.f, ns2 = 0.f, nt2 = 0.f;
    for (int j = q; j < 128; j += 16) {
      const float a = X[(size_t)s * 128 + j];
      const float b = X[(size_t)t * 128 + j];
      ds2 += a * b; ns2 += a * a; nt2 += b * b;
      Arow[142 + j] = a; Arow[270 + j] = b; Arow[398 + j] = fabsf(a - b);
    }
    ds2 += __shfl_xor(ds2, 1); ds2 += __shfl_xor(ds2, 2); ds2 += __shfl_xor(ds2, 4); ds2 += __shfl_xor(ds2, 8);
    ns2 += __shfl_xor(ns2, 1); ns2 += __shfl_xor(ns2, 2); ns2 += __shfl_xor(ns2, 4); ns2 += __shfl_xor(ns2, 8);
    nt2 += __shfl_xor(nt2, 1); nt2 += __shfl_xor(nt2, 2); nt2 += __shfl_xor(nt2, 4); nt2 += __shfl_xor(nt2, 8);
    if (q == 0)
      Arow[526] = ds2 / (fmaxf(sqrtf(ns2), EPSC) * fmaxf(sqrtf(nt2), EPSC));
  }

  float* sHid = sFeat;   // fp32 hidden overlays feature region (post-barrier)
  tile_gemm<16, 256, true>(sFeat, 527, 527, sB, We1, be1, 16,
      [&](int e, int u, float v) { sHid[e * 257 + u] = v; });
  tile_gemm<16, 128, false>(sHid, 257, 256, sB, We2, be2, 16,
      [&](int e, int u, float v) { EB[(size_t)(e0 + e) * 128 + u] = __float2half(v); });
}

// ---------------------------------------------------------------------------
// K2b: msg = relu([xs | e] @ Wmsg + b); atomic segment-sum into AGG[trg].
// 32 edges/block (E = 32*15625). LDS ~41.2KB.
// ---------------------------------------------------------------------------
__global__ __launch_bounds__(256, 3) void k_msg(
    const int* __restrict__ ei, const float* __restrict__ X,
    const fp16* __restrict__ EB,
    const float* __restrict__ Wmsg, const float* __restrict__ bmsg,
    float* __restrict__ AGG)
{
  __shared__ float sA[32 * 257];
  __shared__ __align__(16) float sB[16 * 128];
  __shared__ int strg[32];
  const int tid = threadIdx.x;
  const long e0 = (long)blockIdx.x * 32;
  const int n = tid >> 3;
  const int q = tid & 7;

  {
    const int s = ei[e0 + n];
    if (q == 0) strg[n] = ei[(long)EE + e0 + n];
    for (int j = q; j < 128; j += 8) {
      sA[n * 257 + j]       = X[(size_t)s * 128 + j];
      sA[n * 257 + 128 + j] = __half2float(EB[(size_t)(e0 + n) * 128 + j]);
    }
  }

  tile_gemm<32, 128, true>(sA, 257, 256, sB, Wmsg, bmsg, 32,
      [&](int e, int u, float v) {
        atomicAdd(&AGG[(size_t)strg[e] * 128 + u], v);
      });
}

// ---------------------------------------------------------------------------
// K3: xn = relu([x | agg] @ Wnode + b). 32 nodes/block. LDS ~41.2KB.
// ---------------------------------------------------------------------------
__global__ __launch_bounds__(256, 3) void k_node_update(
    const float* __restrict__ X, const float* __restrict__ AGG,
    const float* __restrict__ Wnode, const float* __restrict__ bnode,
    float* __restrict__ XN)
{
  __shared__ float sA[32 * 257];
  __shared__ __align__(16) float sB[16 * 128];
  const int tid = threadIdx.x;
  const int n0 = blockIdx.x * 32;
  const int remn = NN - n0;
  const int cnt = remn < 32 ? remn : 32;
  const int n = tid >> 3;
  const int q = tid & 7;

  if (n < cnt) {
    for (int j = q; j < 128; j += 8) {
      sA[n * 257 + j]       = X[(size_t)(n0 + n) * 128 + j];
      sA[n * 257 + 128 + j] = AGG[(size_t)(n0 + n) * 128 + j];
    }
  } else {
    for (int j = q; j < 256; j += 8) sA[n * 257 + j] = 0.f;
  }

  tile_gemm<32, 128, true>(sA, 257, 256, sB, Wnode, bnode, cnt,
      [&](int e, int u, float v) { XN[(size_t)(n0 + e) * 128 + u] = v; });
}

// ---------------------------------------------------------------------------
// K4: e_mp = MLP([xn_s|xn_t|e], 384->256->128); pred = MLP(e_mp, 128->64->1).
// 16 edges/block. ALL intermediates overlay sF (post-barrier safe):
//   feat rows: stride 388, cols 0..383         (16*388 = 6208 floats)
//   H2  rows: stride 257 at offset 0           (4112 floats, dead feat region)
//   e_mp rows: stride 129 at offset 4112       (2064; 4112+2064=6176 <= 6208)
//   HC  rows: stride 65 at offset 0            (1040, dead H2 region)
// LDS = 24832 + 16384 = 41.2KB; __launch_bounds__(256,3) caps VGPR ~170
// -> 3 blocks/CU (was 61.9KB + VGPR 256 -> 12% occupancy).
// ---------------------------------------------------------------------------
__global__ __launch_bounds__(256, 3) void k_empl(
    const int* __restrict__ ei, const float* __restrict__ XN,
    const fp16* __restrict__ EB,
    const float* __restrict__ Wmp1, const float* __restrict__ bmp1,
    const float* __restrict__ Wmp2, const float* __restrict__ bmp2,
    const float* __restrict__ Wc1, const float* __restrict__ bc1,
    const float* __restrict__ Wc2, const float* __restrict__ bc2,
    float* __restrict__ out)
{
  __shared__ float sF[16 * 388];
  __shared__ __align__(16) float sB[16 * 256];
  const int tid = threadIdx.x;
  const long e0 = (long)blockIdx.x * 16;
  const int n = tid >> 4;
  const int q = tid & 15;

  {
    const int s = ei[e0 + n];
    const int t = ei[(long)EE + e0 + n];
    for (int j = q; j < 128; j += 16) {
      sF[n * 388 + j]       = XN[(size_t)s * 128 + j];
      sF[n * 388 + 128 + j] = XN[(size_t)t * 128 + j];
      sF[n * 388 + 256 + j] = __half2float(EB[(size_t)(e0 + n) * 128 + j]);
    }
  }

  float* sH2 = sF;            // stride 257, offset 0
  float* sE  = sF + 4112;     // stride 129
  float* sHC = sF;            // stride 65, offset 0 (H2 dead by then)
  tile_gemm<16, 256, true>(sF, 388, 384, sB, Wmp1, bmp1, 16,
      [&](int e, int u, float v) { sH2[e * 257 + u] = v; });
  tile_gemm<16, 128, false>(sH2, 257, 256, sB, Wmp2, bmp2, 16,
      [&](int e, int u, float v) { sE[e * 129 + u] = v; });
  tile_gemm<16, 64, true>(sE, 129, 128, sB, Wc1, bc1, 16,
      [&](int e, int u, float v) { sHC[e * 65 + u] = v; });
  __syncthreads();
  if (tid < 16) {
    float acc = bc2[0];
    for (int k = 0; k < 64; ++k) acc += sHC[tid * 65 + k] * Wc2[k];
    out[e0 + tid] = acc;                 // FP32 output
  }
}

// ---------------------------------------------------------------------------
extern "C" void kernel_launch(void* const* d_in, const int* in_sizes, int n_in,
                              void* d_out, int out_size, void* d_ws, size_t ws_size,
                              hipStream_t stream)
{
  const float* x1  = (const float*)d_in[0];
  const float* x2  = (const float*)d_in[1];
  const int*   ei  = (const int*)d_in[2];
  const float* Wh1 = (const float*)d_in[3],  *bh1 = (const float*)d_in[4];
  const float* Wh2 = (const float*)d_in[5],  *bh2 = (const float*)d_in[6];
  const float* Wl1 = (const float*)d_in[7],  *bl1 = (const float*)d_in[8];
  const float* Wl2 = (const float*)d_in[9],  *bl2 = (const float*)d_in[10];
  const float* We1 = (const float*)d_in[11], *be1 = (const float*)d_in[12];
  const float* We2 = (const float*)d_in[13], *be2 = (const float*)d_in[14];
  const float* Wmsg = (const float*)d_in[15], *bmsg = (const float*)d_in[16];
  const float* Wnode = (const float*)d_in[17], *bnode = (const float*)d_in[18];
  const float* Wmp1 = (const float*)d_in[19], *bmp1 = (const float*)d_in[20];
  const float* Wmp2 = (const float*)d_in[21], *bmp2 = (const float*)d_in[22];
  const float* Wc1 = (const float*)d_in[23], *bc1 = (const float*)d_in[24];
  const float* Wc2 = (const float*)d_in[25], *bc2 = (const float*)d_in[26];
  float* out = (float*)d_out;            // FP32 output buffer

  // ws: X fp32 | XN fp32 | AGG fp32 | EB fp16 = 204.8MB (proven to fit)
  float* X   = (float*)d_ws;
  float* XN  = X  + (size_t)NN * 128;
  float* AGG = XN + (size_t)NN * 128;
  fp16*  EB  = (fp16*)(AGG + (size_t)NN * 128);

  hipMemsetAsync(AGG, 0, (size_t)NN * 128 * sizeof(float), stream);
  k_node_enc<<<12500, 256, 0, stream>>>(x1, x2, Wh1, bh1, Wh2, bh2,
                                        Wl1, bl1, Wl2, bl2, X);
  k_edge_mlp<<<31250, 256, 0, stream>>>(x1, x2, ei, X, We1, be1, We2, be2, EB);
  k_msg<<<15625, 256, 0, stream>>>(ei, X, EB, Wmsg, bmsg, AGG);
  k_node_update<<<1563, 256, 0, stream>>>(X, AGG, Wnode, bnode, XN);
  k_empl<<<31250, 256, 0, stream>>>(ei, XN, EB, Wmp1, bmp1, Wmp2, bmp2,
                                    Wc1, bc1, Wc2, bc2, out);
}

// Round 11
// 10170.557 us; speedup vs baseline: 2.8687x; 1.4901x over previous
//
#include <hip/hip_runtime.h>
#include <hip/hip_bf16.h>
#include <hip/hip_fp16.h>

// CellTrack GNN, MI355X — R11: amortize weight staging (fp16 A, big tiles).
// R10: 15.16ms. k_empl 8.3ms with VALUBusy 21%, TCC traffic 23.6GB/dispatch:
// 16-edge blocks re-stage 557KB of weights each (17.4GB total) and thrash L2.
// R11: k_empl 64 edges/block (4x less weight traffic, fp16 A-tiles, KT=8),
// k_edge_mlp 32 edges (2x), k_msg 64 edges (4x). float4/half2 gathers.
// ws: X fp32 | XN fp32 | AGG fp32 | EB fp16 = 204.8MB (proven).

using bf16 = __hip_bfloat16;
using fp16 = __half;

#define NN 50000
#define EE 500000
#define EPSC 1e-8f

__device__ __forceinline__ float reluf(float v){ return v > 0.f ? v : 0.f; }
__device__ __forceinline__ float toF(float v){ return v; }
__device__ __forceinline__ float toF(fp16 v){ return __half2float(v); }

// ---------------------------------------------------------------------------
// LDS-tiled GEMM: C[ROWS][UDIM] = act(A[ROWS][kdim] @ W + b). A (fp32|fp16)
// in LDS, row stride lda (elements). W,b fp32 global, row-major [kdim][UDIM].
// 256 threads. Thread (ug=tid&15, eg=tid>>4): rows RPT*eg..+RPT-1, units
// ug*UPT..+UPT-1. sB k-tile (KT rows) CHUNK-PERMUTED so thread ug's i-th
// float4 sits at i*64+ug*4 (banks 4ug -> 2-way aliasing only, free per m136).
// ---------------------------------------------------------------------------
template<int ROWS, int UDIM, int KT, bool RELU, typename AT, typename F>
__device__ __forceinline__ void tile_gemm(const AT* sA, int lda, int kdim,
    float* sB, const float* __restrict__ W, const float* __restrict__ bias,
    int cnt, F emit)
{
  constexpr int UPT = UDIM / 16;
  constexpr int NF4 = UPT / 4;
  constexpr int RPT = ROWS / 16;
  constexpr int USH = (UDIM == 256) ? 8 : ((UDIM == 128) ? 7 : 6);
  const int tid = threadIdx.x;
  const int ug = tid & 15;
  const int eg = tid >> 4;
  float acc[RPT][UPT];
#pragma unroll
  for (int r = 0; r < RPT; ++r)
#pragma unroll
    for (int u = 0; u < UPT; ++u) acc[r][u] = 0.f;

  for (int k0 = 0; k0 < kdim; k0 += KT) {
    const int kt = (kdim - k0) < KT ? (kdim - k0) : KT;
    __syncthreads();                      // sB reuse; orders prior sA writes
    for (int L = tid; L < kt * UDIM; L += 256) {
      const int kk = L >> USH;
      const int col = L & (UDIM - 1);
      int pos;
      if (UDIM == 256)      pos = ((col >> 2) & 3) * 64 + ((col >> 4) & 15) * 4 + (col & 3);
      else if (UDIM == 128) pos = ((col >> 2) & 1) * 64 + ((col >> 3) & 15) * 4 + (col & 3);
      else                  pos = col;
      sB[(kk << USH) + pos] = W[(size_t)(k0 + kk) * UDIM + col];
    }
    __syncthreads();
    for (int kk = 0; kk < kt; ++kk) {
      float a[RPT];
#pragma unroll
      for (int r = 0; r < RPT; ++r)
        a[r] = toF(sA[(RPT * eg + r) * lda + k0 + kk]);
#pragma unroll
      for (int i = 0; i < NF4; ++i) {
        const float4 bv = *reinterpret_cast<const float4*>(&sB[(kk << USH) + i * 64 + ug * 4]);
#pragma unroll
        for (int r = 0; r < RPT; ++r) {
          acc[r][i*4+0] += a[r] * bv.x;
          acc[r][i*4+1] += a[r] * bv.y;
          acc[r][i*4+2] += a[r] * bv.z;
          acc[r][i*4+3] += a[r] * bv.w;
        }
      }
    }
  }
  __syncthreads();                        // all sA reads done before emit
#pragma unroll
  for (int r = 0; r < RPT; ++r) {
    const int e = RPT * eg + r;
    if (e < cnt) {
#pragma unroll
      for (int i = 0; i < NF4; ++i)
#pragma unroll
        for (int jj = 0; jj < 4; ++jj) {
          const int u = ug * UPT + i * 4 + jj;
          float v = acc[r][i * 4 + jj] + bias[u];
          if (RELU) v = reluf(v);
          emit(e, u, v);
        }
    }
  }
}

// ---------------------------------------------------------------------------
// K0: node encoder (unchanged). 4 nodes/block (N = 4*12500). LDS ~21KB.
// ---------------------------------------------------------------------------
__global__ __launch_bounds__(256) void k_node_enc(
    const float* __restrict__ x1, const float* __restrict__ x2,
    const float* __restrict__ Wh1, const float* __restrict__ bh1,
    const float* __restrict__ Wh2, const float* __restrict__ bh2,
    const float* __restrict__ Wl1, const float* __restrict__ bl1,
    const float* __restrict__ Wl2, const float* __restrict__ bl2,
    float* __restrict__ X)
{
  __shared__ float sx1[4][13];
  __shared__ float sx2[4][128];
  __shared__ float sh1[4][257];
  __shared__ float sh2[4][257];
  const int tid = threadIdx.x;
  const int node0 = blockIdx.x * 4;

  if (tid < 52) {
    const int n = tid / 13, k = tid % 13;
    sx1[n][k] = x1[(node0 + n) * 13 + k];
  }
  for (int L = tid; L < 512; L += 256) {
    const int n = L >> 7, k = L & 127;
    sx2[n][k] = x2[(size_t)(node0 + n) * 128 + k];
  }
  __syncthreads();

  {
    const int u = tid;
    float a0 = 0.f, a1 = 0.f, a2 = 0.f, a3 = 0.f;
    for (int k = 0; k < 13; ++k) {
      const float w = Wh1[k * 256 + u];
      a0 += sx1[0][k] * w; a1 += sx1[1][k] * w;
      a2 += sx1[2][k] * w; a3 += sx1[3][k] * w;
    }
    const float b = bh1[u];
    sh1[0][u] = reluf(a0 + b); sh1[1][u] = reluf(a1 + b);
    sh1[2][u] = reluf(a2 + b); sh1[3][u] = reluf(a3 + b);

    float c0 = 0.f, c1 = 0.f, c2 = 0.f, c3 = 0.f;
    for (int k = 0; k < 128; ++k) {
      const float w = Wl1[k * 256 + u];
      c0 += sx2[0][k] * w; c1 += sx2[1][k] * w;
      c2 += sx2[2][k] * w; c3 += sx2[3][k] * w;
    }
    const float b2 = bl1[u];
    sh2[0][u] = reluf(c0 + b2); sh2[1][u] = reluf(c1 + b2);
    sh2[2][u] = reluf(c2 + b2); sh2[3][u] = reluf(c3 + b2);
  }
  __syncthreads();

  {
    const int c = tid & 127;
    const int half = tid >> 7;
    float a0 = 0.f, a1 = 0.f;
    if (c < 32) {
      for (int k = 0; k < 256; ++k) {
        const float w = Wh2[k * 32 + c];
        a0 += sh1[half][k] * w; a1 += sh1[half + 2][k] * w;
      }
      const float b = bh2[c];
      X[(size_t)(node0 + half) * 128 + c]     = a0 + b;
      X[(size_t)(node0 + half + 2) * 128 + c] = a1 + b;
    } else {
      const int cc = c - 32;
      for (int k = 0; k < 256; ++k) {
        const float w = Wl2[k * 96 + cc];
        a0 += sh2[half][k] * w; a1 += sh2[half + 2][k] * w;
      }
      const float b = bl2[cc];
      X[(size_t)(node0 + half) * 128 + c]     = a0 + b;
      X[(size_t)(node0 + half + 2) * 128 + c] = a1 + b;
    }
  }
}

// ---------------------------------------------------------------------------
// K2a: edge features + e-MLP (527->256->128) -> EB. 32 edges/block
// (E = 32*15625), 8 threads/edge. Features fp16 in sFeat (stride 528);
// sHid fp16 overlays sFeat post-barrier. LDS 33.8+8 = 41.8KB, 3 blocks/CU.
// ---------------------------------------------------------------------------
__global__ __launch_bounds__(256, 3) void k_edge_mlp(
    const float* __restrict__ x1, const float* __restrict__ x2,
    const int* __restrict__ ei, const float* __restrict__ X,
    const float* __restrict__ We1, const float* __restrict__ be1,
    const float* __restrict__ We2, const float* __restrict__ be2,
    fp16* __restrict__ EB)
{
  __shared__ __align__(16) fp16 sFeat[32 * 528];
  __shared__ __align__(16) float sB[8 * 256];
  const int tid = threadIdx.x;
  const long e0 = (long)blockIdx.x * 32;
  const int n = tid >> 3;        // edge row 0..31
  const int q = tid & 7;         // 8 threads/edge
  fp16* Arow = &sFeat[n * 528];

  {
    const int s = ei[e0 + n];
    const int t = ei[(long)EE + e0 + n];
    float ds = 0.f, ns = 0.f, nt = 0.f;
    for (int j = q; j < 141; j += 8) {
      const float a = (j < 13) ? x1[s * 13 + j] : x2[(size_t)s * 128 + (j - 13)];
      const float b = (j < 13) ? x1[t * 13 + j] : x2[(size_t)t * 128 + (j - 13)];
      ds += a * b; ns += a * a; nt += b * b;
      Arow[j] = __float2half(fabsf(a - b));
    }
    ds += __shfl_xor(ds, 1); ds += __shfl_xor(ds, 2); ds += __shfl_xor(ds, 4);
    ns += __shfl_xor(ns, 1); ns += __shfl_xor(ns, 2); ns += __shfl_xor(ns, 4);
    nt += __shfl_xor(nt, 1); nt += __shfl_xor(nt, 2); nt += __shfl_xor(nt, 4);
    if (q == 0)
      Arow[141] = __float2half(ds / (fmaxf(sqrtf(ns), EPSC) * fmaxf(sqrtf(nt), EPSC)));
    float ds2 = 0.f, ns2 = 0.f, nt2 = 0.f;
    const float4* xsr = (const float4*)&X[(size_t)s * 128];
    const float4* xtr = (const float4*)&X[(size_t)t * 128];
    for (int j4 = q; j4 < 32; j4 += 8) {
      const float4 a = xsr[j4];
      const float4 b = xtr[j4];
      ds2 += a.x*b.x + a.y*b.y + a.z*b.z + a.w*b.w;
      ns2 += a.x*a.x + a.y*a.y + a.z*a.z + a.w*a.w;
      nt2 += b.x*b.x + b.y*b.y + b.z*b.z + b.w*b.w;
      __half2* ps = (__half2*)&Arow[142 + j4 * 4];
      ps[0] = __floats2half2_rn(a.x, a.y); ps[1] = __floats2half2_rn(a.z, a.w);
      __half2* pt = (__half2*)&Arow[270 + j4 * 4];
      pt[0] = __floats2half2_rn(b.x, b.y); pt[1] = __floats2half2_rn(b.z, b.w);
      __half2* pd = (__half2*)&Arow[398 + j4 * 4];
      pd[0] = __floats2half2_rn(fabsf(a.x-b.x), fabsf(a.y-b.y));
      pd[1] = __floats2half2_rn(fabsf(a.z-b.z), fabsf(a.w-b.w));
    }
    ds2 += __shfl_xor(ds2, 1); ds2 += __shfl_xor(ds2, 2); ds2 += __shfl_xor(ds2, 4);
    ns2 += __shfl_xor(ns2, 1); ns2 += __shfl_xor(ns2, 2); ns2 += __shfl_xor(ns2, 4);
    nt2 += __shfl_xor(nt2, 1); nt2 += __shfl_xor(nt2, 2); nt2 += __shfl_xor(nt2, 4);
    if (q == 0)
      Arow[526] = __float2half(ds2 / (fmaxf(sqrtf(ns2), EPSC) * fmaxf(sqrtf(nt2), EPSC)));
  }

  fp16* sHid = sFeat;   // stride 257, overlays features post-barrier
  tile_gemm<32, 256, 8, true, fp16>(sFeat, 528, 527, sB, We1, be1, 32,
      [&](int e, int u, float v) { sHid[e * 257 + u] = __float2half(v); });
  tile_gemm<32, 128, 8, false, fp16>(sHid, 257, 256, sB, We2, be2, 32,
      [&](int e, int u, float v) { EB[(size_t)(e0 + e) * 128 + u] = __float2half(v); });
}

// ---------------------------------------------------------------------------
// K2b: msg = relu([xs|e] @ Wmsg + b); atomic segsum into AGG[trg].
// 64 edges/block (grid 7813, last cnt=32), 4 threads/edge, fp16 A stride 258.
// LDS 33.0+4.1 = 37.1KB, 4 blocks/CU.
// ---------------------------------------------------------------------------
__global__ __launch_bounds__(256, 4) void k_msg(
    const int* __restrict__ ei, const float* __restrict__ X,
    const fp16* __restrict__ EB,
    const float* __restrict__ Wmsg, const float* __restrict__ bmsg,
    float* __restrict__ AGG)
{
  __shared__ __align__(16) fp16 sA[64 * 258];
  __shared__ __align__(16) float sB[8 * 128];
  __shared__ int strg[64];
  const int tid = threadIdx.x;
  const long e0 = (long)blockIdx.x * 64;
  const long rem = (long)EE - e0;
  const int cnt = rem < 64 ? (int)rem : 64;
  const int n = tid >> 2;
  const int q = tid & 3;

  if (n < cnt) {
    const int s = ei[e0 + n];
    if (q == 0) strg[n] = ei[(long)EE + e0 + n];
    const float4* xsr = (const float4*)&X[(size_t)s * 128];
    const __half2* ebr = (const __half2*)&EB[(size_t)(e0 + n) * 128];
    for (int j4 = q; j4 < 32; j4 += 4) {
      const float4 a = xsr[j4];
      __half2* p0 = (__half2*)&sA[n * 258 + j4 * 4];
      p0[0] = __floats2half2_rn(a.x, a.y); p0[1] = __floats2half2_rn(a.z, a.w);
      __half2* p1 = (__half2*)&sA[n * 258 + 128 + j4 * 4];
      p1[0] = ebr[j4 * 2]; p1[1] = ebr[j4 * 2 + 1];
    }
  } else {
    const __half2 z = __floats2half2_rn(0.f, 0.f);
    for (int j4 = q; j4 < 32; j4 += 4) {
      __half2* p0 = (__half2*)&sA[n * 258 + j4 * 4];
      p0[0] = z; p0[1] = z;
      __half2* p1 = (__half2*)&sA[n * 258 + 128 + j4 * 4];
      p1[0] = z; p1[1] = z;
    }
  }

  tile_gemm<64, 128, 8, true, fp16>(sA, 258, 256, sB, Wmsg, bmsg, cnt,
      [&](int e, int u, float v) {
        atomicAdd(&AGG[(size_t)strg[e] * 128 + u], v);
      });
}

// ---------------------------------------------------------------------------
// K3: xn = relu([x|agg] @ Wnode + b). 32 nodes/block, fp32 A. LDS 37KB.
// ---------------------------------------------------------------------------
__global__ __launch_bounds__(256, 4) void k_node_update(
    const float* __restrict__ X, const float* __restrict__ AGG,
    const float* __restrict__ Wnode, const float* __restrict__ bnode,
    float* __restrict__ XN)
{
  __shared__ float sA[32 * 257];
  __shared__ __align__(16) float sB[8 * 128];
  const int tid = threadIdx.x;
  const int n0 = blockIdx.x * 32;
  const int remn = NN - n0;
  const int cnt = remn < 32 ? remn : 32;
  const int n = tid >> 3;
  const int q = tid & 7;

  if (n < cnt) {
    for (int j = q; j < 128; j += 8) {
      sA[n * 257 + j]       = X[(size_t)(n0 + n) * 128 + j];
      sA[n * 257 + 128 + j] = AGG[(size_t)(n0 + n) * 128 + j];
    }
  } else {
    for (int j = q; j < 256; j += 8) sA[n * 257 + j] = 0.f;
  }

  tile_gemm<32, 128, 8, true, float>(sA, 257, 256, sB, Wnode, bnode, cnt,
      [&](int e, int u, float v) { XN[(size_t)(n0 + e) * 128 + u] = v; });
}

// ---------------------------------------------------------------------------
// K4: e_mp = MLP([xn_s|xn_t|e], 384->256->128); pred = MLP(e_mp, 128->64->1).
// 64 edges/block (grid 7813, last cnt=32), 4 threads/edge. fp16 A, overlays:
//   feat rows: fp16 stride 388 (24832 halves = 49.7KB)
//   H2: fp16 stride 257 at half-offset 0 (16448 h, feat dead post-barrier)
//   e_mp: fp16 stride 129 at half-offset 16448 (8256 h; 16448+8256<=24832)
//   HC: fp32 stride 65 at float-offset 0 (4160 fl = 8320 h <= 16448, H2 dead)
// LDS 49.7+8 = 57.9KB -> 2 blocks/CU. Weight staging 557KB/64 edges (was /16).
// ---------------------------------------------------------------------------
__global__ __launch_bounds__(256, 2) void k_empl(
    const int* __restrict__ ei, const float* __restrict__ XN,
    const fp16* __restrict__ EB,
    const float* __restrict__ Wmp1, const float* __restrict__ bmp1,
    const float* __restrict__ Wmp2, const float* __restrict__ bmp2,
    const float* __restrict__ Wc1, const float* __restrict__ bc1,
    const float* __restrict__ Wc2, const float* __restrict__ bc2,
    float* __restrict__ out)
{
  __shared__ __align__(16) fp16 sF[64 * 388];
  __shared__ __align__(16) float sB[8 * 256];
  const int tid = threadIdx.x;
  const long e0 = (long)blockIdx.x * 64;
  const long rem = (long)EE - e0;
  const int cnt = rem < 64 ? (int)rem : 64;
  const int n = tid >> 2;
  const int q = tid & 3;

  if (n < cnt) {
    const int s = ei[e0 + n];
    const int t = ei[(long)EE + e0 + n];
    const float4* xsr = (const float4*)&XN[(size_t)s * 128];
    const float4* xtr = (const float4*)&XN[(size_t)t * 128];
    const __half2* ebr = (const __half2*)&EB[(size_t)(e0 + n) * 128];
    for (int j4 = q; j4 < 32; j4 += 4) {
      const float4 a = xsr[j4];
      __half2* p0 = (__half2*)&sF[n * 388 + j4 * 4];
      p0[0] = __floats2half2_rn(a.x, a.y); p0[1] = __floats2half2_rn(a.z, a.w);
      const float4 b = xtr[j4];
      __half2* p1 = (__half2*)&sF[n * 388 + 128 + j4 * 4];
      p1[0] = __floats2half2_rn(b.x, b.y); p1[1] = __floats2half2_rn(b.z, b.w);
      __half2* p2 = (__half2*)&sF[n * 388 + 256 + j4 * 4];
      p2[0] = ebr[j4 * 2]; p2[1] = ebr[j4 * 2 + 1];
    }
  } else {
    const __half2 z = __floats2half2_rn(0.f, 0.f);
    for (int j4 = q; j4 < 32; j4 += 4) {
      ((__half2*)&sF[n * 388 + j4 * 4])[0] = z;
      ((__half2*)&sF[n * 388 + j4 * 4])[1] = z;
      ((__half2*)&sF[n * 388 + 128 + j4 * 4])[0] = z;
      ((__half2*)&sF[n * 388 + 128 + j4 * 4])[1] = z;
      ((__half2*)&sF[n * 388 + 256 + j4 * 4])[0] = z;
      ((__half2*)&sF[n * 388 + 256 + j4 * 4])[1] = z;
    }
  }

  fp16*  sH2 = sF;                    // stride 257 halves
  fp16*  sE  = sF + 16448;            // stride 129 halves
  float* sHC = (float*)sF;            // stride 65 floats (H2 region, dead)
  tile_gemm<64, 256, 8, true, fp16>(sF, 388, 384, sB, Wmp1, bmp1, 64,
      [&](int e, int u, float v) { sH2[e * 257 + u] = __float2half(v); });
  tile_gemm<64, 128, 8, false, fp16>(sH2, 257, 256, sB, Wmp2, bmp2, 64,
      [&](int e, int u, float v) { sE[e * 129 + u] = __float2half(v); });
  tile_gemm<64, 64, 8, true, fp16>(sE, 129, 128, sB, Wc1, bc1, 64,
      [&](int e, int u, float v) { sHC[e * 65 + u] = v; });
  __syncthreads();
  if (tid < cnt) {
    float acc = bc2[0];
    for (int k = 0; k < 64; ++k) acc += sHC[tid * 65 + k] * Wc2[k];
    out[e0 + tid] = acc;               // FP32 output
  }
}

// ---------------------------------------------------------------------------
extern "C" void kernel_launch(void* const* d_in, const int* in_sizes, int n_in,
                              void* d_out, int out_size, void* d_ws, size_t ws_size,
                              hipStream_t stream)
{
  const float* x1  = (const float*)d_in[0];
  const float* x2  = (const float*)d_in[1];
  const int*   ei  = (const int*)d_in[2];
  const float* Wh1 = (const float*)d_in[3],  *bh1 = (const float*)d_in[4];
  const float* Wh2 = (const float*)d_in[5],  *bh2 = (const float*)d_in[6];
  const float* Wl1 = (const float*)d_in[7],  *bl1 = (const float*)d_in[8];
  const float* Wl2 = (const float*)d_in[9],  *bl2 = (const float*)d_in[10];
  const float* We1 = (const float*)d_in[11], *be1 = (const float*)d_in[12];
  const float* We2 = (const float*)d_in[13], *be2 = (const float*)d_in[14];
  const float* Wmsg = (const float*)d_in[15], *bmsg = (const float*)d_in[16];
  const float* Wnode = (const float*)d_in[17], *bnode = (const float*)d_in[18];
  const float* Wmp1 = (const float*)d_in[19], *bmp1 = (const float*)d_in[20];
  const float* Wmp2 = (const float*)d_in[21], *bmp2 = (const float*)d_in[22];
  const float* Wc1 = (const float*)d_in[23], *bc1 = (const float*)d_in[24];
  const float* Wc2 = (const float*)d_in[25], *bc2 = (const float*)d_in[26];
  float* out = (float*)d_out;

  // ws: X fp32 | XN fp32 | AGG fp32 | EB fp16 = 204.8MB (proven to fit)
  float* X   = (float*)d_ws;
  float* XN  = X  + (size_t)NN * 128;
  float* AGG = XN + (size_t)NN * 128;
  fp16*  EB  = (fp16*)(AGG + (size_t)NN * 128);

  hipMemsetAsync(AGG, 0, (size_t)NN * 128 * sizeof(float), stream);
  k_node_enc<<<12500, 256, 0, stream>>>(x1, x2, Wh1, bh1, Wh2, bh2,
                                        Wl1, bl1, Wl2, bl2, X);
  k_edge_mlp<<<15625, 256, 0, stream>>>(x1, x2, ei, X, We1, be1, We2, be2, EB);
  k_msg<<<7813, 256, 0, stream>>>(ei, X, EB, Wmsg, bmsg, AGG);
  k_node_update<<<1563, 256, 0, stream>>>(X, AGG, Wnode, bnode, XN);
  k_empl<<<7813, 256, 0, stream>>>(ei, XN, EB, Wmp1, bmp1, Wmp2, bmp2,
                                   Wc1, bc1, Wc2, bc2, out);
}

// Round 12
// 1445.576 us; speedup vs baseline: 20.1832x; 7.0356x over previous
//
#include <hip/hip_runtime.h>
#include <hip/hip_bf16.h>
#include <hip/hip_fp16.h>

// CellTrack GNN, MI355X — R12: MFMA (f32_16x16x32_f16) for all edge GEMMs.
// R11: 10.2ms, k_edge_mlp 5ms VALU-bound (MfmaUtil 0). R12: weights prepped
// once to fp16 transposed [n][k] (k-padded to 32) in ws; B-frags read direct
// from L2-resident WT (16B global loads, no LDS-B, no K-loop barriers);
// A fp16 in LDS, stride ≡ 8 mod 16 halves (2-way banks, free). Mappings:
// A[m=lane&15][k=quad*8+j], B[k=quad*8+j][n=lane&15], D col=lane&15,
// row=quad*4+reg (m89/m91-verified). ws: X(=XN alias) | AGG | EB fp16 | WT
// = 180MB (< proven 204.8MB).

using fp16 = __half;
typedef _Float16 h16;
typedef _Float16 f16x8 __attribute__((ext_vector_type(8)));
typedef float f32x4 __attribute__((ext_vector_type(4)));

#define NN 50000
#define EE 500000
#define EPSC 1e-8f

__device__ __forceinline__ float reluf(float v){ return v > 0.f ? v : 0.f; }

// WT sub-buffer offsets (halves)
#define OFF_E1   0         // [256][544]  (527 real)
#define OFF_E2   139264    // [128][256]
#define OFF_MSG  172032    // [128][256]
#define OFF_NODE 204800    // [128][256]
#define OFF_MP1  237568    // [256][384]
#define OFF_MP2  335872    // [128][256]
#define OFF_C1   368640    // [64][128]
#define WT_TOTAL 376832

// ---------------------------------------------------------------------------
// k_prep: fp32 weights -> fp16 transposed [n][kP] (zero-pad k >= kreal).
// ---------------------------------------------------------------------------
__global__ __launch_bounds__(256) void k_prep(
    const float* __restrict__ We1, const float* __restrict__ We2,
    const float* __restrict__ Wmsg, const float* __restrict__ Wnode,
    const float* __restrict__ Wmp1, const float* __restrict__ Wmp2,
    const float* __restrict__ Wc1, h16* __restrict__ WT)
{
  int idx = blockIdx.x * 256 + threadIdx.x;
  if (idx >= WT_TOTAL) return;
  h16 v;
  if (idx < OFF_E2) {
    const int L = idx, n = L / 544, k = L % 544;
    v = (h16)((k < 527) ? We1[k * 256 + n] : 0.f);
  } else if (idx < OFF_MSG) {
    const int L = idx - OFF_E2, n = L >> 8, k = L & 255;
    v = (h16)We2[k * 128 + n];
  } else if (idx < OFF_NODE) {
    const int L = idx - OFF_MSG, n = L >> 8, k = L & 255;
    v = (h16)Wmsg[k * 128 + n];
  } else if (idx < OFF_MP1) {
    const int L = idx - OFF_NODE, n = L >> 8, k = L & 255;
    v = (h16)Wnode[k * 128 + n];
  } else if (idx < OFF_MP2) {
    const int L = idx - OFF_MP1, n = L / 384, k = L % 384;
    v = (h16)Wmp1[k * 256 + n];
  } else if (idx < OFF_C1) {
    const int L = idx - OFF_MP2, n = L >> 8, k = L & 255;
    v = (h16)Wmp2[k * 128 + n];
  } else {
    const int L = idx - OFF_C1, n = L >> 7, k = L & 127;
    v = (h16)Wc1[k * 64 + n];
  }
  WT[idx] = v;
}

// ---------------------------------------------------------------------------
// MFMA GEMM: C[ROWS][UDIM] = act(A[ROWS][kP] @ WT^T + b). 256 thr = 4 waves.
// Wave w: all ROWS x cols [w*UDIM/4, ..). A: fp16 LDS stride lda (mult 8,
// ≡8 mod 16). WT: fp16 global [UDIM][kP]. Barriers: one before emits (A-reads
// done -> overlays safe), one after (emits visible).
// ---------------------------------------------------------------------------
template<int ROWS, int UDIM, bool RELU, typename F>
__device__ __forceinline__ void mfma_gemm(const h16* sA, int lda, int kP,
    const h16* __restrict__ WT, const float* __restrict__ bias, F emit)
{
  constexpr int RT = ROWS / 16;
  constexpr int NPW = UDIM / 4;
  constexpr int NT = NPW / 16;
  const int tid = threadIdx.x;
  const int wave = tid >> 6;
  const int lane = tid & 63;
  const int m = lane & 15;
  const int quad = lane >> 4;
  const int n0 = wave * NPW;
  f32x4 acc[RT][NT];
#pragma unroll
  for (int r = 0; r < RT; ++r)
#pragma unroll
    for (int j = 0; j < NT; ++j) acc[r][j] = (f32x4){0.f, 0.f, 0.f, 0.f};

  for (int k0 = 0; k0 < kP; k0 += 32) {
    f16x8 bf[NT];
#pragma unroll
    for (int j = 0; j < NT; ++j)
      bf[j] = *reinterpret_cast<const f16x8*>(
          &WT[(size_t)(n0 + j * 16 + m) * kP + k0 + quad * 8]);
#pragma unroll
    for (int r = 0; r < RT; ++r) {
      const f16x8 af = *reinterpret_cast<const f16x8*>(
          &sA[(r * 16 + m) * lda + k0 + quad * 8]);
#pragma unroll
      for (int j = 0; j < NT; ++j)
        acc[r][j] = __builtin_amdgcn_mfma_f32_16x16x32_f16(af, bf[j], acc[r][j], 0, 0, 0);
    }
  }
  __syncthreads();
#pragma unroll
  for (int r = 0; r < RT; ++r)
#pragma unroll
    for (int j = 0; j < NT; ++j) {
      const int col = n0 + j * 16 + m;
      const float bb = bias[col];
#pragma unroll
      for (int g = 0; g < 4; ++g) {
        const int row = r * 16 + quad * 4 + g;
        float v = acc[r][j][g] + bb;
        if (RELU) v = reluf(v);
        emit(row, col, v);
      }
    }
  __syncthreads();
}

// ---------------------------------------------------------------------------
// K0: node encoder (fp32 VALU, unchanged — 3.4 GMAC total). 4 nodes/block.
// ---------------------------------------------------------------------------
__global__ __launch_bounds__(256) void k_node_enc(
    const float* __restrict__ x1, const float* __restrict__ x2,
    const float* __restrict__ Wh1, const float* __restrict__ bh1,
    const float* __restrict__ Wh2, const float* __restrict__ bh2,
    const float* __restrict__ Wl1, const float* __restrict__ bl1,
    const float* __restrict__ Wl2, const float* __restrict__ bl2,
    float* __restrict__ X)
{
  __shared__ float sx1[4][13];
  __shared__ float sx2[4][128];
  __shared__ float sh1[4][257];
  __shared__ float sh2[4][257];
  const int tid = threadIdx.x;
  const int node0 = blockIdx.x * 4;

  if (tid < 52) {
    const int n = tid / 13, k = tid % 13;
    sx1[n][k] = x1[(node0 + n) * 13 + k];
  }
  for (int L = tid; L < 512; L += 256) {
    const int n = L >> 7, k = L & 127;
    sx2[n][k] = x2[(size_t)(node0 + n) * 128 + k];
  }
  __syncthreads();

  {
    const int u = tid;
    float a0 = 0.f, a1 = 0.f, a2 = 0.f, a3 = 0.f;
    for (int k = 0; k < 13; ++k) {
      const float w = Wh1[k * 256 + u];
      a0 += sx1[0][k] * w; a1 += sx1[1][k] * w;
      a2 += sx1[2][k] * w; a3 += sx1[3][k] * w;
    }
    const float b = bh1[u];
    sh1[0][u] = reluf(a0 + b); sh1[1][u] = reluf(a1 + b);
    sh1[2][u] = reluf(a2 + b); sh1[3][u] = reluf(a3 + b);

    float c0 = 0.f, c1 = 0.f, c2 = 0.f, c3 = 0.f;
    for (int k = 0; k < 128; ++k) {
      const float w = Wl1[k * 256 + u];
      c0 += sx2[0][k] * w; c1 += sx2[1][k] * w;
      c2 += sx2[2][k] * w; c3 += sx2[3][k] * w;
    }
    const float b2 = bl1[u];
    sh2[0][u] = reluf(c0 + b2); sh2[1][u] = reluf(c1 + b2);
    sh2[2][u] = reluf(c2 + b2); sh2[3][u] = reluf(c3 + b2);
  }
  __syncthreads();

  {
    const int c = tid & 127;
    const int half = tid >> 7;
    float a0 = 0.f, a1 = 0.f;
    if (c < 32) {
      for (int k = 0; k < 256; ++k) {
        const float w = Wh2[k * 32 + c];
        a0 += sh1[half][k] * w; a1 += sh1[half + 2][k] * w;
      }
      const float b = bh2[c];
      X[(size_t)(node0 + half) * 128 + c]     = a0 + b;
      X[(size_t)(node0 + half + 2) * 128 + c] = a1 + b;
    } else {
      const int cc = c - 32;
      for (int k = 0; k < 256; ++k) {
        const float w = Wl2[k * 96 + cc];
        a0 += sh2[half][k] * w; a1 += sh2[half + 2][k] * w;
      }
      const float b = bl2[cc];
      X[(size_t)(node0 + half) * 128 + c]     = a0 + b;
      X[(size_t)(node0 + half + 2) * 128 + c] = a1 + b;
    }
  }
}

// ---------------------------------------------------------------------------
// K2a: edge features + e-MLP (544p->256->128) -> EB. 32 edges/block
// (E = 32*15625), 8 thr/edge. sFeat fp16 [32][552] 34.5KB; hid overlays
// (stride 264). LDS -> 4 blocks/CU.
// ---------------------------------------------------------------------------
__global__ __launch_bounds__(256, 4) void k_edge_mlp(
    const float* __restrict__ x1, const float* __restrict__ x2,
    const int* __restrict__ ei, const float* __restrict__ X,
    const h16* __restrict__ WT,
    const float* __restrict__ be1, const float* __restrict__ be2,
    h16* __restrict__ EB)
{
  __shared__ __align__(16) h16 sFeat[32 * 552];
  const int tid = threadIdx.x;
  const long e0 = (long)blockIdx.x * 32;
  const int n = tid >> 3;
  const int q = tid & 7;
  h16* Arow = &sFeat[n * 552];

  {
    const int s = ei[e0 + n];
    const int t = ei[(long)EE + e0 + n];
    float ds = 0.f, ns = 0.f, nt = 0.f;
    for (int j = q; j < 141; j += 8) {
      const float a = (j < 13) ? x1[s * 13 + j] : x2[(size_t)s * 128 + (j - 13)];
      const float b = (j < 13) ? x1[t * 13 + j] : x2[(size_t)t * 128 + (j - 13)];
      ds += a * b; ns += a * a; nt += b * b;
      Arow[j] = (h16)fabsf(a - b);
    }
    ds += __shfl_xor(ds, 1); ds += __shfl_xor(ds, 2); ds += __shfl_xor(ds, 4);
    ns += __shfl_xor(ns, 1); ns += __shfl_xor(ns, 2); ns += __shfl_xor(ns, 4);
    nt += __shfl_xor(nt, 1); nt += __shfl_xor(nt, 2); nt += __shfl_xor(nt, 4);
    if (q == 0)
      Arow[141] = (h16)(ds / (fmaxf(sqrtf(ns), EPSC) * fmaxf(sqrtf(nt), EPSC)));
    float ds2 = 0.f, ns2 = 0.f, nt2 = 0.f;
    const float4* xsr = (const float4*)&X[(size_t)s * 128];
    const float4* xtr = (const float4*)&X[(size_t)t * 128];
    for (int j4 = q; j4 < 32; j4 += 8) {
      const float4 a = xsr[j4];
      const float4 b = xtr[j4];
      ds2 += a.x*b.x + a.y*b.y + a.z*b.z + a.w*b.w;
      ns2 += a.x*a.x + a.y*a.y + a.z*a.z + a.w*a.w;
      nt2 += b.x*b.x + b.y*b.y + b.z*b.z + b.w*b.w;
      h16* ps = &Arow[142 + j4 * 4];
      ps[0] = (h16)a.x; ps[1] = (h16)a.y; ps[2] = (h16)a.z; ps[3] = (h16)a.w;
      h16* pt = &Arow[270 + j4 * 4];
      pt[0] = (h16)b.x; pt[1] = (h16)b.y; pt[2] = (h16)b.z; pt[3] = (h16)b.w;
      h16* pd = &Arow[398 + j4 * 4];
      pd[0] = (h16)fabsf(a.x - b.x); pd[1] = (h16)fabsf(a.y - b.y);
      pd[2] = (h16)fabsf(a.z - b.z); pd[3] = (h16)fabsf(a.w - b.w);
    }
    ds2 += __shfl_xor(ds2, 1); ds2 += __shfl_xor(ds2, 2); ds2 += __shfl_xor(ds2, 4);
    ns2 += __shfl_xor(ns2, 1); ns2 += __shfl_xor(ns2, 2); ns2 += __shfl_xor(ns2, 4);
    nt2 += __shfl_xor(nt2, 1); nt2 += __shfl_xor(nt2, 2); nt2 += __shfl_xor(nt2, 4);
    if (q == 0)
      Arow[526] = (h16)(ds2 / (fmaxf(sqrtf(ns2), EPSC) * fmaxf(sqrtf(nt2), EPSC)));
    for (int j = 527 + q; j < 544; j += 8) Arow[j] = (h16)0.f;   // k-pad
  }
  __syncthreads();

  h16* sHid = sFeat;   // stride 264, overlays (post-barrier in mfma_gemm)
  mfma_gemm<32, 256, true>(sFeat, 552, 544, WT + OFF_E1, be1,
      [&](int row, int col, float v) { sHid[row * 264 + col] = (h16)v; });
  mfma_gemm<32, 128, false>(sHid, 264, 256, WT + OFF_E2, be2,
      [&](int row, int col, float v) {
        EB[(size_t)(e0 + row) * 128 + col] = (h16)v; });
}

// ---------------------------------------------------------------------------
// K2b: msg = relu([xs|e] @ Wmsg + b); atomic segsum. 64 edges/block
// (grid 7813, last cnt=32). sA fp16 [64][264] 33KB.
// ---------------------------------------------------------------------------
__global__ __launch_bounds__(256, 4) void k_msg(
    const int* __restrict__ ei, const float* __restrict__ X,
    const h16* __restrict__ EB, const h16* __restrict__ WT,
    const float* __restrict__ bmsg, float* __restrict__ AGG)
{
  __shared__ __align__(16) h16 sA[64 * 264];
  __shared__ int strg[64];
  const int tid = threadIdx.x;
  const long e0 = (long)blockIdx.x * 64;
  const long rem = (long)EE - e0;
  const int cnt = rem < 64 ? (int)rem : 64;
  const int n = tid >> 2;
  const int q = tid & 3;

  if (n < cnt) {
    const int s = ei[e0 + n];
    if (q == 0) strg[n] = ei[(long)EE + e0 + n];
    const float4* xsr = (const float4*)&X[(size_t)s * 128];
    const f16x8* ebr = (const f16x8*)&EB[(size_t)(e0 + n) * 128];
    for (int j4 = q; j4 < 32; j4 += 4) {
      const float4 a = xsr[j4];
      h16* p0 = &sA[n * 264 + j4 * 4];
      p0[0] = (h16)a.x; p0[1] = (h16)a.y; p0[2] = (h16)a.z; p0[3] = (h16)a.w;
    }
    for (int j8 = q; j8 < 16; j8 += 4)
      *(f16x8*)&sA[n * 264 + 128 + j8 * 8] = ebr[j8];
  } else {
    for (int j = q; j < 64; j += 4)
      *(h16*)&((int*)&sA[n * 264])[j] = (h16)0.f;  // cheap-ish zero
    for (int j = q * 4; j < 256; j += 16) {
      sA[n * 264 + j] = (h16)0.f; sA[n * 264 + j + 1] = (h16)0.f;
      sA[n * 264 + j + 2] = (h16)0.f; sA[n * 264 + j + 3] = (h16)0.f;
    }
  }
  __syncthreads();

  mfma_gemm<64, 128, true>(sA, 264, 256, WT + OFF_MSG, bmsg,
      [&](int row, int col, float v) {
        if (row < cnt) atomicAdd(&AGG[(size_t)strg[row] * 128 + col], v);
      });
}

// ---------------------------------------------------------------------------
// K3: xn = relu([x|agg] @ Wnode + b). 64 nodes/block (grid 782, last 16).
// XN aliases X (per-block read-then-write of own rows only — safe).
// ---------------------------------------------------------------------------
__global__ __launch_bounds__(256, 4) void k_node_update(
    const float* __restrict__ X, const float* __restrict__ AGG,
    const h16* __restrict__ WT, const float* __restrict__ bnode,
    float* __restrict__ XN)
{
  __shared__ __align__(16) h16 sA[64 * 264];
  const int tid = threadIdx.x;
  const int n0 = blockIdx.x * 64;
  const int remn = NN - n0;
  const int cnt = remn < 64 ? remn : 64;
  const int n = tid >> 2;
  const int q = tid & 3;

  if (n < cnt) {
    const float4* xr = (const float4*)&X[(size_t)(n0 + n) * 128];
    const float4* ar = (const float4*)&AGG[(size_t)(n0 + n) * 128];
    for (int j4 = q; j4 < 32; j4 += 4) {
      const float4 a = xr[j4];
      h16* p0 = &sA[n * 264 + j4 * 4];
      p0[0] = (h16)a.x; p0[1] = (h16)a.y; p0[2] = (h16)a.z; p0[3] = (h16)a.w;
      const float4 b = ar[j4];
      h16* p1 = &sA[n * 264 + 128 + j4 * 4];
      p1[0] = (h16)b.x; p1[1] = (h16)b.y; p1[2] = (h16)b.z; p1[3] = (h16)b.w;
    }
  } else {
    for (int j = q; j < 256; j += 4) sA[n * 264 + j] = (h16)0.f;
  }
  __syncthreads();

  mfma_gemm<64, 128, true>(sA, 264, 256, WT + OFF_NODE, bnode,
      [&](int row, int col, float v) {
        if (row < cnt) XN[(size_t)(n0 + row) * 128 + col] = v;
      });
}

// ---------------------------------------------------------------------------
// K4: e_mp = MLP([xn_s|xn_t|e], 384->256->128); pred = MLP(e_mp, 128->64->1).
// 64 edges/block (grid 7813, last 32). sF fp16 [64][392] = 49KB; overlays:
//   H2 stride 264 at 0 (16896h <= 25088); e_mp stride 136 at 0 (post-H2-read);
//   HC fp32 at byte 17408 (disjoint from e_mp bytes 0..17407).
// ---------------------------------------------------------------------------
__global__ __launch_bounds__(256, 3) void k_empl(
    const int* __restrict__ ei, const float* __restrict__ XN,
    const h16* __restrict__ EB, const h16* __restrict__ WT,
    const float* __restrict__ bmp1, const float* __restrict__ bmp2,
    const float* __restrict__ bc1,
    const float* __restrict__ Wc2, const float* __restrict__ bc2,
    float* __restrict__ out)
{
  __shared__ __align__(16) h16 sF[64 * 392];
  const int tid = threadIdx.x;
  const long e0 = (long)blockIdx.x * 64;
  const long rem = (long)EE - e0;
  const int cnt = rem < 64 ? (int)rem : 64;
  const int n = tid >> 2;
  const int q = tid & 3;

  if (n < cnt) {
    const int s = ei[e0 + n];
    const int t = ei[(long)EE + e0 + n];
    const float4* xsr = (const float4*)&XN[(size_t)s * 128];
    const float4* xtr = (const float4*)&XN[(size_t)t * 128];
    const f16x8* ebr = (const f16x8*)&EB[(size_t)(e0 + n) * 128];
    for (int j4 = q; j4 < 32; j4 += 4) {
      const float4 a = xsr[j4];
      h16* p0 = &sF[n * 392 + j4 * 4];
      p0[0] = (h16)a.x; p0[1] = (h16)a.y; p0[2] = (h16)a.z; p0[3] = (h16)a.w;
      const float4 b = xtr[j4];
      h16* p1 = &sF[n * 392 + 128 + j4 * 4];
      p1[0] = (h16)b.x; p1[1] = (h16)b.y; p1[2] = (h16)b.z; p1[3] = (h16)b.w;
    }
    for (int j8 = q; j8 < 16; j8 += 4)
      *(f16x8*)&sF[n * 392 + 256 + j8 * 8] = ebr[j8];
  } else {
    for (int j = q; j < 384; j += 4) sF[n * 392 + j] = (h16)0.f;
  }
  __syncthreads();

  h16*  sH2 = sF;                              // stride 264
  h16*  sE  = sF;                              // stride 136 (over dead H2)
  float* sHC = (float*)((char*)sF + 17408);    // stride 65 fp32, disjoint
  mfma_gemm<64, 256, true>(sF, 392, 384, WT + OFF_MP1, bmp1,
      [&](int row, int col, float v) { sH2[row * 264 + col] = (h16)v; });
  mfma_gemm<64, 128, false>(sH2, 264, 256, WT + OFF_MP2, bmp2,
      [&](int row, int col, float v) { sE[row * 136 + col] = (h16)v; });
  mfma_gemm<64, 64, true>(sE, 136, 128, WT + OFF_C1, bc1,
      [&](int row, int col, float v) { sHC[row * 65 + col] = v; });
  if (tid < cnt) {
    float acc = bc2[0];
    for (int k = 0; k < 64; ++k) acc += sHC[tid * 65 + k] * Wc2[k];
    out[e0 + tid] = acc;
  }
}

// ---------------------------------------------------------------------------
extern "C" void kernel_launch(void* const* d_in, const int* in_sizes, int n_in,
                              void* d_out, int out_size, void* d_ws, size_t ws_size,
                              hipStream_t stream)
{
  const float* x1  = (const float*)d_in[0];
  const float* x2  = (const float*)d_in[1];
  const int*   ei  = (const int*)d_in[2];
  const float* Wh1 = (const float*)d_in[3],  *bh1 = (const float*)d_in[4];
  const float* Wh2 = (const float*)d_in[5],  *bh2 = (const float*)d_in[6];
  const float* Wl1 = (const float*)d_in[7],  *bl1 = (const float*)d_in[8];
  const float* Wl2 = (const float*)d_in[9],  *bl2 = (const float*)d_in[10];
  const float* We1 = (const float*)d_in[11], *be1 = (const float*)d_in[12];
  const float* We2 = (const float*)d_in[13], *be2 = (const float*)d_in[14];
  const float* Wmsg = (const float*)d_in[15], *bmsg = (const float*)d_in[16];
  const float* Wnode = (const float*)d_in[17], *bnode = (const float*)d_in[18];
  const float* Wmp1 = (const float*)d_in[19], *bmp1 = (const float*)d_in[20];
  const float* Wmp2 = (const float*)d_in[21], *bmp2 = (const float*)d_in[22];
  const float* Wc1 = (const float*)d_in[23], *bc1 = (const float*)d_in[24];
  const float* Wc2 = (const float*)d_in[25], *bc2 = (const float*)d_in[26];
  float* out = (float*)d_out;

  // ws: X fp32 (=XN alias) | AGG fp32 | EB fp16 | WT fp16  = ~180MB
  float* X   = (float*)d_ws;
  float* AGG = X + (size_t)NN * 128;
  h16*   EB  = (h16*)(AGG + (size_t)NN * 128);
  h16*   WT  = EB + (size_t)EE * 128;
  float* XN  = X;   // alias (k_node_update: per-block read-then-write own rows)

  k_prep<<<(WT_TOTAL + 255) / 256, 256, 0, stream>>>(
      We1, We2, Wmsg, Wnode, Wmp1, Wmp2, Wc1, WT);
  hipMemsetAsync(AGG, 0, (size_t)NN * 128 * sizeof(float), stream);
  k_node_enc<<<12500, 256, 0, stream>>>(x1, x2, Wh1, bh1, Wh2, bh2,
                                        Wl1, bl1, Wl2, bl2, X);
  k_edge_mlp<<<15625, 256, 0, stream>>>(x1, x2, ei, X, WT, be1, be2, EB);
  k_msg<<<7813, 256, 0, stream>>>(ei, X, EB, WT, bmsg, AGG);
  k_node_update<<<782, 256, 0, stream>>>(X, AGG, WT, bnode, XN);
  k_empl<<<7813, 256, 0, stream>>>(ei, XN, EB, WT, bmp1, bmp2, bc1,
                                   Wc2, bc2, out);
}

// Round 13
// 1345.155 us; speedup vs baseline: 21.6899x; 1.0747x over previous
//
#include <hip/hip_runtime.h>
#include <hip/hip_bf16.h>
#include <hip/hip_fp16.h>

// CellTrack GNN, MI355X — R13: fp16 gather mirrors + msg fused into edge-MLP.
// R12: 1.45ms; k_edge_mlp 571us gather-bound (FETCH 546MB, MfmaUtil 13%).
// R13: all gathered tensors fp16 (X1H/X2H prep; XH/XNH stored fp16 at the
// producer) -> gather bytes halved; k_msg folded into k_edge_mlp (xs kept in
// sMsg tile, e appended after layer2, third MFMA + atomic segsum).
// ws: AGG fp32 | EB fp16 | WT fp16 | XH | XNH | X1H | X2H  = ~194MB.

using fp16 = __half;
typedef _Float16 h16;
typedef _Float16 f16x8 __attribute__((ext_vector_type(8)));
typedef float f32x4 __attribute__((ext_vector_type(4)));

#define NN 50000
#define EE 500000
#define EPSC 1e-8f

__device__ __forceinline__ float reluf(float v){ return v > 0.f ? v : 0.f; }

// WT sub-buffer offsets (halves)
#define OFF_E1   0         // [256][544]  (527 real)
#define OFF_E2   139264    // [128][256]
#define OFF_MSG  172032    // [128][256]
#define OFF_NODE 204800    // [128][256]
#define OFF_MP1  237568    // [256][384]
#define OFF_MP2  335872    // [128][256]
#define OFF_C1   368640    // [64][128]
#define WT_TOTAL 376832

// ---------------------------------------------------------------------------
// k_prep: fp32 weights -> fp16 transposed [n][kP] (zero-pad k >= kreal).
// ---------------------------------------------------------------------------
__global__ __launch_bounds__(256) void k_prep(
    const float* __restrict__ We1, const float* __restrict__ We2,
    const float* __restrict__ Wmsg, const float* __restrict__ Wnode,
    const float* __restrict__ Wmp1, const float* __restrict__ Wmp2,
    const float* __restrict__ Wc1, h16* __restrict__ WT)
{
  int idx = blockIdx.x * 256 + threadIdx.x;
  if (idx >= WT_TOTAL) return;
  h16 v;
  if (idx < OFF_E2) {
    const int L = idx, n = L / 544, k = L % 544;
    v = (h16)((k < 527) ? We1[k * 256 + n] : 0.f);
  } else if (idx < OFF_MSG) {
    const int L = idx - OFF_E2, n = L >> 8, k = L & 255;
    v = (h16)We2[k * 128 + n];
  } else if (idx < OFF_NODE) {
    const int L = idx - OFF_MSG, n = L >> 8, k = L & 255;
    v = (h16)Wmsg[k * 128 + n];
  } else if (idx < OFF_MP1) {
    const int L = idx - OFF_NODE, n = L >> 8, k = L & 255;
    v = (h16)Wnode[k * 128 + n];
  } else if (idx < OFF_MP2) {
    const int L = idx - OFF_MP1, n = L / 384, k = L % 384;
    v = (h16)Wmp1[k * 256 + n];
  } else if (idx < OFF_C1) {
    const int L = idx - OFF_MP2, n = L >> 8, k = L & 255;
    v = (h16)Wmp2[k * 128 + n];
  } else {
    const int L = idx - OFF_C1, n = L >> 7, k = L & 127;
    v = (h16)Wc1[k * 64 + n];
  }
  WT[idx] = v;
}

// k_cvt: x1/x2 -> fp16 mirrors (gather-byte halving)
__global__ __launch_bounds__(256) void k_cvt(
    const float* __restrict__ x1, const float* __restrict__ x2,
    h16* __restrict__ X1H, h16* __restrict__ X2H)
{
  const int idx = blockIdx.x * 256 + threadIdx.x;
  if (idx < NN * 13) X1H[idx] = (h16)x1[idx];
  const int i2 = idx - NN * 13;
  if (i2 >= 0 && i2 < NN * 128) X2H[i2] = (h16)x2[i2];
}

// ---------------------------------------------------------------------------
// MFMA GEMM: C[ROWS][UDIM] = act(A[ROWS][kP] @ WT^T + b). 256 thr = 4 waves.
// Wave w: all ROWS x cols [w*UDIM/4..). A fp16 LDS stride lda (≡8 mod 16).
// WT fp16 global [UDIM][kP] (L2-resident). Barrier before emits (A reads
// done -> overlays safe) and after (emits visible).
// ---------------------------------------------------------------------------
template<int ROWS, int UDIM, bool RELU, typename F>
__device__ __forceinline__ void mfma_gemm(const h16* sA, int lda, int kP,
    const h16* __restrict__ WT, const float* __restrict__ bias, F emit)
{
  constexpr int RT = ROWS / 16;
  constexpr int NPW = UDIM / 4;
  constexpr int NT = NPW / 16;
  const int tid = threadIdx.x;
  const int wave = tid >> 6;
  const int lane = tid & 63;
  const int m = lane & 15;
  const int quad = lane >> 4;
  const int n0 = wave * NPW;
  f32x4 acc[RT][NT];
#pragma unroll
  for (int r = 0; r < RT; ++r)
#pragma unroll
    for (int j = 0; j < NT; ++j) acc[r][j] = (f32x4){0.f, 0.f, 0.f, 0.f};

  for (int k0 = 0; k0 < kP; k0 += 32) {
    f16x8 bf[NT];
#pragma unroll
    for (int j = 0; j < NT; ++j)
      bf[j] = *reinterpret_cast<const f16x8*>(
          &WT[(size_t)(n0 + j * 16 + m) * kP + k0 + quad * 8]);
#pragma unroll
    for (int r = 0; r < RT; ++r) {
      const f16x8 af = *reinterpret_cast<const f16x8*>(
          &sA[(r * 16 + m) * lda + k0 + quad * 8]);
#pragma unroll
      for (int j = 0; j < NT; ++j)
        acc[r][j] = __builtin_amdgcn_mfma_f32_16x16x32_f16(af, bf[j], acc[r][j], 0, 0, 0);
    }
  }
  __syncthreads();
#pragma unroll
  for (int r = 0; r < RT; ++r)
#pragma unroll
    for (int j = 0; j < NT; ++j) {
      const int col = n0 + j * 16 + m;
      const float bb = bias[col];
#pragma unroll
      for (int g = 0; g < 4; ++g) {
        const int row = r * 16 + quad * 4 + g;
        float v = acc[r][j][g] + bb;
        if (RELU) v = reluf(v);
        emit(row, col, v);
      }
    }
  __syncthreads();
}

// ---------------------------------------------------------------------------
// K0: node encoder (fp32 VALU). 4 nodes/block. Output: XH fp16.
// ---------------------------------------------------------------------------
__global__ __launch_bounds__(256) void k_node_enc(
    const float* __restrict__ x1, const float* __restrict__ x2,
    const float* __restrict__ Wh1, const float* __restrict__ bh1,
    const float* __restrict__ Wh2, const float* __restrict__ bh2,
    const float* __restrict__ Wl1, const float* __restrict__ bl1,
    const float* __restrict__ Wl2, const float* __restrict__ bl2,
    h16* __restrict__ XH)
{
  __shared__ float sx1[4][13];
  __shared__ float sx2[4][128];
  __shared__ float sh1[4][257];
  __shared__ float sh2[4][257];
  const int tid = threadIdx.x;
  const int node0 = blockIdx.x * 4;

  if (tid < 52) {
    const int n = tid / 13, k = tid % 13;
    sx1[n][k] = x1[(node0 + n) * 13 + k];
  }
  for (int L = tid; L < 512; L += 256) {
    const int n = L >> 7, k = L & 127;
    sx2[n][k] = x2[(size_t)(node0 + n) * 128 + k];
  }
  __syncthreads();

  {
    const int u = tid;
    float a0 = 0.f, a1 = 0.f, a2 = 0.f, a3 = 0.f;
    for (int k = 0; k < 13; ++k) {
      const float w = Wh1[k * 256 + u];
      a0 += sx1[0][k] * w; a1 += sx1[1][k] * w;
      a2 += sx1[2][k] * w; a3 += sx1[3][k] * w;
    }
    const float b = bh1[u];
    sh1[0][u] = reluf(a0 + b); sh1[1][u] = reluf(a1 + b);
    sh1[2][u] = reluf(a2 + b); sh1[3][u] = reluf(a3 + b);

    float c0 = 0.f, c1 = 0.f, c2 = 0.f, c3 = 0.f;
    for (int k = 0; k < 128; ++k) {
      const float w = Wl1[k * 256 + u];
      c0 += sx2[0][k] * w; c1 += sx2[1][k] * w;
      c2 += sx2[2][k] * w; c3 += sx2[3][k] * w;
    }
    const float b2 = bl1[u];
    sh2[0][u] = reluf(c0 + b2); sh2[1][u] = reluf(c1 + b2);
    sh2[2][u] = reluf(c2 + b2); sh2[3][u] = reluf(c3 + b2);
  }
  __syncthreads();

  {
    const int c = tid & 127;
    const int half = tid >> 7;
    float a0 = 0.f, a1 = 0.f;
    if (c < 32) {
      for (int k = 0; k < 256; ++k) {
        const float w = Wh2[k * 32 + c];
        a0 += sh1[half][k] * w; a1 += sh1[half + 2][k] * w;
      }
      const float b = bh2[c];
      XH[(size_t)(node0 + half) * 128 + c]     = (h16)(a0 + b);
      XH[(size_t)(node0 + half + 2) * 128 + c] = (h16)(a1 + b);
    } else {
      const int cc = c - 32;
      for (int k = 0; k < 256; ++k) {
        const float w = Wl2[k * 96 + cc];
        a0 += sh2[half][k] * w; a1 += sh2[half + 2][k] * w;
      }
      const float b = bl2[cc];
      XH[(size_t)(node0 + half) * 128 + c]     = (h16)(a0 + b);
      XH[(size_t)(node0 + half + 2) * 128 + c] = (h16)(a1 + b);
    }
  }
}

// ---------------------------------------------------------------------------
// K2: FUSED edge features + e-MLP (544p->256->128) + msg GEMM + atomic segsum.
// 32 edges/block (E = 32*15625), 8 thr/edge. All gathers fp16.
// sFeat [32][552] 34.5KB (hid overlays, stride 264); sMsg [32][264] 16.5KB
// holds [xs | e]. LDS ~52.3KB -> 3 blocks/CU.
// ---------------------------------------------------------------------------
__global__ __launch_bounds__(256, 3) void k_edge_mlp(
    const h16* __restrict__ X1H, const h16* __restrict__ X2H,
    const int* __restrict__ ei, const h16* __restrict__ XH,
    const h16* __restrict__ WT,
    const float* __restrict__ be1, const float* __restrict__ be2,
    const float* __restrict__ bmsg,
    h16* __restrict__ EB, float* __restrict__ AGG)
{
  __shared__ __align__(16) h16 sFeat[32 * 552];
  __shared__ __align__(16) h16 sMsg[32 * 264];
  __shared__ int strg[32];
  const int tid = threadIdx.x;
  const long e0 = (long)blockIdx.x * 32;
  const int n = tid >> 3;
  const int q = tid & 7;
  h16* Arow = &sFeat[n * 552];

  {
    const int s = ei[e0 + n];
    const int t = ei[(long)EE + e0 + n];
    if (q == 0) strg[n] = t;
    float ds = 0.f, ns = 0.f, nt = 0.f;
    for (int j = q; j < 141; j += 8) {
      const float a = (j < 13) ? (float)X1H[s * 13 + j]
                               : (float)X2H[(size_t)s * 128 + (j - 13)];
      const float b = (j < 13) ? (float)X1H[t * 13 + j]
                               : (float)X2H[(size_t)t * 128 + (j - 13)];
      ds += a * b; ns += a * a; nt += b * b;
      Arow[j] = (h16)fabsf(a - b);
    }
    ds += __shfl_xor(ds, 1); ds += __shfl_xor(ds, 2); ds += __shfl_xor(ds, 4);
    ns += __shfl_xor(ns, 1); ns += __shfl_xor(ns, 2); ns += __shfl_xor(ns, 4);
    nt += __shfl_xor(nt, 1); nt += __shfl_xor(nt, 2); nt += __shfl_xor(nt, 4);
    if (q == 0)
      Arow[141] = (h16)(ds / (fmaxf(sqrtf(ns), EPSC) * fmaxf(sqrtf(nt), EPSC)));
    float ds2 = 0.f, ns2 = 0.f, nt2 = 0.f;
    for (int j = q; j < 128; j += 8) {
      const h16 ah = XH[(size_t)s * 128 + j];
      const h16 bh = XH[(size_t)t * 128 + j];
      const float a = (float)ah, b = (float)bh;
      ds2 += a * b; ns2 += a * a; nt2 += b * b;
      Arow[142 + j] = ah; Arow[270 + j] = bh; Arow[398 + j] = (h16)fabsf(a - b);
      sMsg[n * 264 + j] = ah;          // xs for the msg GEMM
    }
    ds2 += __shfl_xor(ds2, 1); ds2 += __shfl_xor(ds2, 2); ds2 += __shfl_xor(ds2, 4);
    ns2 += __shfl_xor(ns2, 1); ns2 += __shfl_xor(ns2, 2); ns2 += __shfl_xor(ns2, 4);
    nt2 += __shfl_xor(nt2, 1); nt2 += __shfl_xor(nt2, 2); nt2 += __shfl_xor(nt2, 4);
    if (q == 0)
      Arow[526] = (h16)(ds2 / (fmaxf(sqrtf(ns2), EPSC) * fmaxf(sqrtf(nt2), EPSC)));
    for (int j = 527 + q; j < 544; j += 8) Arow[j] = (h16)0.f;   // k-pad
  }
  __syncthreads();

  h16* sHid = sFeat;   // stride 264, overlays features (post-barrier)
  mfma_gemm<32, 256, true>(sFeat, 552, 544, WT + OFF_E1, be1,
      [&](int row, int col, float v) { sHid[row * 264 + col] = (h16)v; });
  mfma_gemm<32, 128, false>(sHid, 264, 256, WT + OFF_E2, be2,
      [&](int row, int col, float v) {
        const h16 vh = (h16)v;
        EB[(size_t)(e0 + row) * 128 + col] = vh;
        sMsg[row * 264 + 128 + col] = vh;          // e beside xs
      });
  mfma_gemm<32, 128, true>(sMsg, 264, 256, WT + OFF_MSG, bmsg,
      [&](int row, int col, float v) {
        atomicAdd(&AGG[(size_t)strg[row] * 128 + col], v);
      });
}

// ---------------------------------------------------------------------------
// K3: xn = relu([x|agg] @ Wnode + b). 64 nodes/block (grid 782, last 16).
// Reads XH fp16 + AGG fp32; writes XNH fp16.
// ---------------------------------------------------------------------------
__global__ __launch_bounds__(256, 4) void k_node_update(
    const h16* __restrict__ XH, const float* __restrict__ AGG,
    const h16* __restrict__ WT, const float* __restrict__ bnode,
    h16* __restrict__ XNH)
{
  __shared__ __align__(16) h16 sA[64 * 264];
  const int tid = threadIdx.x;
  const int n0 = blockIdx.x * 64;
  const int remn = NN - n0;
  const int cnt = remn < 64 ? remn : 64;
  const int n = tid >> 2;
  const int q = tid & 3;

  if (n < cnt) {
    const f16x8* xr = (const f16x8*)&XH[(size_t)(n0 + n) * 128];
    const float4* ar = (const float4*)&AGG[(size_t)(n0 + n) * 128];
    for (int j8 = q; j8 < 16; j8 += 4)
      *(f16x8*)&sA[n * 264 + j8 * 8] = xr[j8];
    for (int j4 = q; j4 < 32; j4 += 4) {
      const float4 b = ar[j4];
      h16* p1 = &sA[n * 264 + 128 + j4 * 4];
      p1[0] = (h16)b.x; p1[1] = (h16)b.y; p1[2] = (h16)b.z; p1[3] = (h16)b.w;
    }
  } else {
    for (int j = q; j < 256; j += 4) sA[n * 264 + j] = (h16)0.f;
  }
  __syncthreads();

  mfma_gemm<64, 128, true>(sA, 264, 256, WT + OFF_NODE, bnode,
      [&](int row, int col, float v) {
        if (row < cnt) XNH[(size_t)(n0 + row) * 128 + col] = (h16)v;
      });
}

// ---------------------------------------------------------------------------
// K4: e_mp = MLP([xn_s|xn_t|e], 384->256->128); pred = MLP(e_mp, 128->64->1).
// 64 edges/block (grid 7813, last 32). All gathers fp16 f16x8 copies.
// sF [64][392] 49KB; overlays: H2 stride 264 @0; e_mp stride 136 @0;
// HC fp32 @byte 17408.
// ---------------------------------------------------------------------------
__global__ __launch_bounds__(256, 3) void k_empl(
    const int* __restrict__ ei, const h16* __restrict__ XNH,
    const h16* __restrict__ EB, const h16* __restrict__ WT,
    const float* __restrict__ bmp1, const float* __restrict__ bmp2,
    const float* __restrict__ bc1,
    const float* __restrict__ Wc2, const float* __restrict__ bc2,
    float* __restrict__ out)
{
  __shared__ __align__(16) h16 sF[64 * 392];
  const int tid = threadIdx.x;
  const long e0 = (long)blockIdx.x * 64;
  const long rem = (long)EE - e0;
  const int cnt = rem < 64 ? (int)rem : 64;
  const int n = tid >> 2;
  const int q = tid & 3;

  if (n < cnt) {
    const int s = ei[e0 + n];
    const int t = ei[(long)EE + e0 + n];
    const f16x8* xsr = (const f16x8*)&XNH[(size_t)s * 128];
    const f16x8* xtr = (const f16x8*)&XNH[(size_t)t * 128];
    const f16x8* ebr = (const f16x8*)&EB[(size_t)(e0 + n) * 128];
    for (int j8 = q; j8 < 16; j8 += 4) {
      *(f16x8*)&sF[n * 392 + j8 * 8]       = xsr[j8];
      *(f16x8*)&sF[n * 392 + 128 + j8 * 8] = xtr[j8];
      *(f16x8*)&sF[n * 392 + 256 + j8 * 8] = ebr[j8];
    }
  } else {
    for (int j = q; j < 384; j += 4) sF[n * 392 + j] = (h16)0.f;
  }
  __syncthreads();

  h16*  sH2 = sF;                              // stride 264
  h16*  sE  = sF;                              // stride 136 (over dead H2)
  float* sHC = (float*)((char*)sF + 17408);    // stride 65 fp32, disjoint
  mfma_gemm<64, 256, true>(sF, 392, 384, WT + OFF_MP1, bmp1,
      [&](int row, int col, float v) { sH2[row * 264 + col] = (h16)v; });
  mfma_gemm<64, 128, false>(sH2, 264, 256, WT + OFF_MP2, bmp2,
      [&](int row, int col, float v) { sE[row * 136 + col] = (h16)v; });
  mfma_gemm<64, 64, true>(sE, 136, 128, WT + OFF_C1, bc1,
      [&](int row, int col, float v) { sHC[row * 65 + col] = v; });
  if (tid < cnt) {
    float acc = bc2[0];
    for (int k = 0; k < 64; ++k) acc += sHC[tid * 65 + k] * Wc2[k];
    out[e0 + tid] = acc;
  }
}

// ---------------------------------------------------------------------------
extern "C" void kernel_launch(void* const* d_in, const int* in_sizes, int n_in,
                              void* d_out, int out_size, void* d_ws, size_t ws_size,
                              hipStream_t stream)
{
  const float* x1  = (const float*)d_in[0];
  const float* x2  = (const float*)d_in[1];
  const int*   ei  = (const int*)d_in[2];
  const float* Wh1 = (const float*)d_in[3],  *bh1 = (const float*)d_in[4];
  const float* Wh2 = (const float*)d_in[5],  *bh2 = (const float*)d_in[6];
  const float* Wl1 = (const float*)d_in[7],  *bl1 = (const float*)d_in[8];
  const float* Wl2 = (const float*)d_in[9],  *bl2 = (const float*)d_in[10];
  const float* We1 = (const float*)d_in[11], *be1 = (const float*)d_in[12];
  const float* We2 = (const float*)d_in[13], *be2 = (const float*)d_in[14];
  const float* Wmsg = (const float*)d_in[15], *bmsg = (const float*)d_in[16];
  const float* Wnode = (const float*)d_in[17], *bnode = (const float*)d_in[18];
  const float* Wmp1 = (const float*)d_in[19], *bmp1 = (const float*)d_in[20];
  const float* Wmp2 = (const float*)d_in[21], *bmp2 = (const float*)d_in[22];
  const float* Wc1 = (const float*)d_in[23], *bc1 = (const float*)d_in[24];
  const float* Wc2 = (const float*)d_in[25], *bc2 = (const float*)d_in[26];
  float* out = (float*)d_out;

  // ws: AGG fp32 | EB fp16 | WT | XH | XNH | X1H | X2H  (~194MB, < 204.8)
  float* AGG = (float*)d_ws;
  h16*   EB  = (h16*)(AGG + (size_t)NN * 128);
  h16*   WT  = EB + (size_t)EE * 128;
  h16*   XH  = WT + WT_TOTAL;
  h16*   XNH = XH + (size_t)NN * 128;
  h16*   X1H = XNH + (size_t)NN * 128;
  h16*   X2H = X1H + (size_t)NN * 13;   // byte offset stays 16B-aligned

  k_prep<<<(WT_TOTAL + 255) / 256, 256, 0, stream>>>(
      We1, We2, Wmsg, Wnode, Wmp1, Wmp2, Wc1, WT);
  k_cvt<<<(NN * 13 + NN * 128 + 255) / 256, 256, 0, stream>>>(x1, x2, X1H, X2H);
  hipMemsetAsync(AGG, 0, (size_t)NN * 128 * sizeof(float), stream);
  k_node_enc<<<12500, 256, 0, stream>>>(x1, x2, Wh1, bh1, Wh2, bh2,
                                        Wl1, bl1, Wl2, bl2, XH);
  k_edge_mlp<<<15625, 256, 0, stream>>>(X1H, X2H, ei, XH, WT,
                                        be1, be2, bmsg, EB, AGG);
  k_node_update<<<782, 256, 0, stream>>>(XH, AGG, WT, bnode, XNH);
  k_empl<<<7813, 256, 0, stream>>>(ei, XNH, EB, WT, bmp1, bmp2, bc1,
                                   Wc2, bc2, out);
}